// Round 1
// baseline (321.882 us; speedup 1.0000x reference)
//
#include <hip/hip_runtime.h>
#include <hip/hip_bf16.h>

// Problem constants (fixed by setup_inputs)
#define NB 16     // batch
#define CC 64     // channels
#define TT 64
#define VV 25
#define LL 1600   // T*V
#define HH 4
#define DD 64
#define NH 64     // N*H

// Dtype contract (rounds 0-3): d_in fp32, d_out fp32, tolerance bf16-grade.
// Round-13 lesson: mfma_16x16x16 costs the same cycles as 16x16x32 -> use
// largest-K shapes only. Round-14 lesson: block supply != concurrency; the
// residency cap (~2.7 blocks/CU) is structural -> attack the non-attn kernels.
// Round-16 (this round): k_attn was serialization-bound (MfmaUtil 16%,
// VALUBusy 42%, 4.3M LDS-conflict cycles). (a) K LDS staging dropped -- K/V
// are XCD-pinned and L2-resident, so direct global loads replace kbuf + the
// 2 barriers/kt; (b) QK^T operands SWAPPED (mfma(K,Q)) so the P tile is
// redistributed to PV A-fragments in-register via v_permlane32/16_swap
// (T12), deleting the P LDS round-trip + fences entirely. The kt loop now
// has zero LDS and zero barriers.

typedef __hip_bfloat16 bf16;
typedef __attribute__((ext_vector_type(8))) short short8;
typedef __attribute__((ext_vector_type(4))) float f32x4;
typedef __attribute__((ext_vector_type(4))) int int4v;
typedef __attribute__((ext_vector_type(4))) unsigned short us4;

__device__ __forceinline__ float b2f(bf16 v) { return __bfloat162float(v); }
__device__ __forceinline__ unsigned short f2bf_bits(float f) {
  bf16 h = __float2bfloat16(f);
  return *(unsigned short*)&h;
}
// pack two f32 -> bf16x2 by truncation: one v_perm_b32 (validated round 14)
__device__ __forceinline__ unsigned pkbf_trunc(float lo, float hi) {
  return __builtin_amdgcn_perm(__float_as_uint(hi), __float_as_uint(lo), 0x07060302u);
}
// xor-1 lane exchange via DPP quad_perm [1,0,3,2] (0xB1): VALU, not LDS.
__device__ __forceinline__ float dppx1(float x) {
  return __int_as_float(
      __builtin_amdgcn_mov_dpp(__float_as_int(x), 0xB1, 0xF, 0xF, true));
}
__device__ __forceinline__ int dppx1i(int x) {
  return __builtin_amdgcn_mov_dpp(x, 0xB1, 0xF, 0xF, true);
}
// gfx950 dual-register lane swaps (CDNA4): both operands read+written.
// v_permlane32_swap: dst lanes 32-63 <-> src lanes 0-31.
// v_permlane16_swap: dst rows 1,3 (lanes 16-31,48-63) <-> src rows 0,2.
__device__ __forceinline__ void pl32swap(int &a, int &b) {
  asm("v_permlane32_swap_b32 %0, %1" : "+v"(a), "+v"(b));
}
__device__ __forceinline__ void pl16swap(int &a, int &b) {
  asm("v_permlane16_swap_b32 %0, %1" : "+v"(a), "+v"(b));
}

// ---------------------------------------------------------------------------
// K0: weight prep (unchanged).
// ---------------------------------------------------------------------------
__global__ void k_prep(const float* __restrict__ Wo, const float* __restrict__ Wf,
                       const float* __restrict__ Wq,
                       bf16* __restrict__ Wt, bf16* __restrict__ WfT,
                       bf16* __restrict__ WqT) {
  int i = blockIdx.x * 256 + threadIdx.x;
  if (i < 147456) {
    int j = i & 7, lane = (i >> 3) & 63, cot = (i >> 9) & 3;
    int kc = (i >> 11) & 7, r = i >> 14;
    int co = cot * 16 + (lane & 15);
    int ci = kc * 32 + (lane >> 4) * 8 + j;
    Wt[i] = __float2bfloat16(Wo[(co * 256 + ci) * 9 + r]);
  }
  if (i < 4096) {
    int j = i & 7, lane = (i >> 3) & 63, cot = (i >> 9) & 3, kc = (i >> 11) & 1;
    int co = cot * 16 + (lane & 15);
    int ci = kc * 32 + (lane >> 4) * 8 + j;
    WfT[i] = __float2bfloat16(Wf[co * 64 + ci]);
  }
  if (i < 49152) {
    int jj = i & 7, lane = (i >> 3) & 63, g = i >> 9;  // g 0..95
    int nt = g % 48, half = g / 48;
    int ch = half * 32 + (lane >> 4) * 8 + jj;
    int j = nt * 16 + (lane & 15);
    WqT[i] = __float2bfloat16(Wq[ch * 768 + j]);
  }
}

// ---------------------------------------------------------------------------
// K1: qkv projection as MFMA GEMM, round-15: flat 12-group loop with B-frag
// PREFETCH across the transpose clobbers (round-9 trick: clobbers pin the
// issue point early; waits land at next group's MFMAs). Groups 0-3 = q,
// 4-7 = k (tile-transpose epilogue), 8-11 = v (direct stores).
// grid 1600, block 64.
// ---------------------------------------------------------------------------
__global__ __launch_bounds__(64)
void k_qkv(const float* __restrict__ x, const bf16* __restrict__ WqT,
           const float* __restrict__ bq,
           bf16* __restrict__ q, bf16* __restrict__ k, bf16* __restrict__ vt) {
  __shared__ short xa[16 * 72];  // A-tile [16 l][64 c] (+pad)
  __shared__ short tr[16 * 66];  // transpose buffer for q/k epilogue
  int lane = threadIdx.x;
  int quad = lane >> 4, c = lane & 15;
  int n = blockIdx.x / 100;
  int l0 = (blockIdx.x % 100) * 16;
  bool ev = (c & 1) == 0;

  {
    int l = c;
    const float* xb = x + (size_t)n * 102400 + (size_t)(quad * 16) * 1600 + l0 + l;
    unsigned short vb[16];
#pragma unroll
    for (int i = 0; i < 16; i++) vb[i] = f2bf_bits(xb[(size_t)i * 1600]);
    unsigned wrds[8];
#pragma unroll
    for (int i = 0; i < 8; i++)
      wrds[i] = ((unsigned)vb[2 * i + 1] << 16) | vb[2 * i];
    *(short8*)(xa + l * 72 + quad * 16) = *(short8*)&wrds[0];
    *(short8*)(xa + l * 72 + quad * 16 + 8) = *(short8*)&wrds[4];
  }
  asm volatile("" ::: "memory");
  short8 af0 = *(const short8*)(xa + c * 72 + quad * 8);
  short8 af1 = *(const short8*)(xa + c * 72 + 32 + quad * 8);

  const short* wq0 = (const short*)WqT;
  const float QSCALE = 0.125f * 1.44269504f;

  short8 bc[8], bn[8];
#pragma unroll
  for (int t = 0; t < 4; t++) {
    bc[2 * t]     = *(const short8*)(wq0 + ((size_t)t * 64 + lane) * 8);
    bc[2 * t + 1] = *(const short8*)(wq0 + ((size_t)(48 + t) * 64 + lane) * 8);
  }

#pragma unroll
  for (int g = 0; g < 12; g++) {
    int s = g >> 2, h = g & 3;
    // --- 4 output tiles of this group (uses prefetched bc) ---
    f32x4 z[4];
#pragma unroll
    for (int t = 0; t < 4; t++) {
      int nt = g * 4 + t;
      float bv = bq[nt * 16 + c];
      f32x4 zz = {bv, bv, bv, bv};
      zz = __builtin_amdgcn_mfma_f32_16x16x32_bf16(af0, bc[2 * t], zz, 0, 0, 0);
      zz = __builtin_amdgcn_mfma_f32_16x16x32_bf16(af1, bc[2 * t + 1], zz, 0, 0, 0);
      z[t] = zz;
    }
    // --- prefetch group g+1 B-frags BEFORE the clobber section ---
    if (g < 11) {
#pragma unroll
      for (int t = 0; t < 4; t++) {
        int nt = (g + 1) * 4 + t;
        bn[2 * t]     = *(const short8*)(wq0 + ((size_t)nt * 64 + lane) * 8);
        bn[2 * t + 1] = *(const short8*)(wq0 + ((size_t)(48 + nt) * 64 + lane) * 8);
      }
    }
    if (s < 2) {
      // q/k: tile-transpose via tr, coalesced 16B row stores
      asm volatile("" ::: "memory");
#pragma unroll
      for (int t = 0; t < 4; t++) {
        if (s == 0) {
#pragma unroll
          for (int r = 0; r < 4; r++) z[t][r] *= QSCALE;
        }
        int us_[4];
#pragma unroll
        for (int r = 0; r < 4; r++) us_[r] = f2bf_bits(z[t][r]);
        int xv0 = dppx1i(us_[0]);
        int xv1 = dppx1i(us_[1]);
        int xv2 = dppx1i(us_[2]);
        int xv3 = dppx1i(us_[3]);
        if (ev) {
          *(int*)(tr + (quad * 4 + 0) * 66 + t * 16 + c) = (xv0 << 16) | us_[0];
          *(int*)(tr + (quad * 4 + 1) * 66 + t * 16 + c) = (xv1 << 16) | us_[1];
        } else {
          *(int*)(tr + (quad * 4 + 2) * 66 + t * 16 + (c - 1)) = (us_[2] << 16) | xv2;
          *(int*)(tr + (quad * 4 + 3) * 66 + t * 16 + (c - 1)) = (us_[3] << 16) | xv3;
        }
      }
      asm volatile("" ::: "memory");
      int row = lane >> 2, seg = lane & 3;
      short8 o0 = *(const short8*)(tr + row * 66 + seg * 16);
      short8 o1 = *(const short8*)(tr + row * 66 + seg * 16 + 8);
      short* dstp = (short*)(s == 0 ? q : k);
      short* dst = dstp + ((size_t)(n * 4 + h) * 1600 + l0 + row) * 64 + seg * 16;
      *(short8*)(dst) = o0;
      *(short8*)(dst + 8) = o1;
      asm volatile("" ::: "memory");  // tr reused next group
    } else {
      // v: direct stores to vt[nh][d][l]
#pragma unroll
      for (int t = 0; t < 4; t++) {
        us4 pk;
#pragma unroll
        for (int r = 0; r < 4; r++) pk[r] = f2bf_bits(z[t][r]);
        *(us4*)((short*)vt + ((size_t)((n * 4 + h) * 64 + t * 16 + c)) * 1600 +
                l0 + quad * 4) = pk;
      }
    }
#pragma unroll
    for (int i = 0; i < 8; i++) bc[i] = bn[i];
  }
}

// ---------------------------------------------------------------------------
// K2: MFMA flash attention, round-16: barrier-free kt loop.
//  - K loaded directly from global (L2-resident, XCD-pinned) -> kbuf gone,
//    both __syncthreads per kt gone, sk prefetch regs freed.
//  - QK^T computed SWAPPED: s = mfma(K_frag, Q_frag) => D[m=kv][n=q]. The
//    PV A-fragments are then assembled IN-REGISTER: pkbf_trunc pairs
//    (kv 2j,2j+1) then one permlane32_swap + one permlane16_swap per
//    ct-pair/word gathers quads (2q,2q+1) -> quad q. No P LDS, no fences.
//  - LDS only holds the once-per-block O-transpose epilogue tile.
// grid split*1600, block 128.
// ---------------------------------------------------------------------------
__global__ __launch_bounds__(128, 2)
void k_attn(const bf16* __restrict__ q, const bf16* __restrict__ k,
            const bf16* __restrict__ vt, bf16* __restrict__ po,
            float* __restrict__ ls, int split) {
  __shared__ short pl_all[2][16 * 66];  // epilogue transpose only (wave-private)
  int tid = threadIdx.x;
  int wv = tid >> 6, lane = tid & 63;
  int quad = lane >> 4, c = lane & 15;
  int bid = blockIdx.x;
  int xcd = bid & 7;
  int slot = bid >> 3;
  int half, qt, grp;
  if (split == 2) { half = slot & 1; qt = (slot >> 1) % 25; grp = slot / 50; }
  else            { half = 0;        qt = slot % 25;        grp = slot / 25; }
  int nh = grp * 8 + xcd;          // nh%8 == bid%8 -> per-XCD K/V stream
  int kt0 = half ? 13 : 0;
  int kt1 = (split == 2 && half == 0) ? 13 : 25;
  int l0 = qt * 64 + wv * 32;      // wave's rows: tiles at l0, l0+16
  short* pl = pl_all[wv];

  const short* qbase = (const short*)q + ((size_t)nh * 1600 + l0 + c) * 64 + quad * 8;
  short8 qf[2][2];
  qf[0][0] = *(const short8*)(qbase);
  qf[0][1] = *(const short8*)(qbase + 32);
  qf[1][0] = *(const short8*)(qbase + 16 * 64);
  qf[1][1] = *(const short8*)(qbase + 16 * 64 + 32);

  short ob = (c == 0) ? (short)0x3F80 : (short)0;  // bf16 1.0 in col 0
  short8 onesf = {ob, ob, ob, ob, ob, ob, ob, ob};

  f32x4 acc[2][5] = {};  // per tile: 4 d-tiles + l-tile (ones-trick)

  const short* kg = (const short*)k + (size_t)nh * 102400;
  const short* vg = (const short*)vt + (size_t)nh * 102400;
  bool ev = (c & 1) == 0;

  for (int kt = kt0; kt < kt1; kt++) {
    // V fragments (B operand of PV), issued early; used at loop end.
    short8 vf[4][2];
#pragma unroll
    for (int ct = 0; ct < 4; ct++) {
      const short* p0 = vg + (size_t)(ct * 16 + c) * 1600 + kt * 64 + quad * 8;
      vf[ct][0] = *(const short8*)(p0);
      vf[ct][1] = *(const short8*)(p0 + 32);
    }
    // QK^T swapped: s[tt][ct] = D[m=kv(ct tile)][n=q(tile tt)], bias -8.
    const short* kr = kg + (size_t)kt * 4096;
    f32x4 s[2][4];
#pragma unroll
    for (int ct = 0; ct < 4; ct++) {
      const short* kp = kr + (size_t)(ct * 16 + c) * 64 + quad * 8;
      short8 kf0 = *(const short8*)(kp);
      short8 kf1 = *(const short8*)(kp + 32);
      f32x4 z0 = {-8.f, -8.f, -8.f, -8.f}, z1 = {-8.f, -8.f, -8.f, -8.f};
      z0 = __builtin_amdgcn_mfma_f32_16x16x32_bf16(kf0, qf[0][0], z0, 0, 0, 0);
      z0 = __builtin_amdgcn_mfma_f32_16x16x32_bf16(kf1, qf[0][1], z0, 0, 0, 0);
      z1 = __builtin_amdgcn_mfma_f32_16x16x32_bf16(kf0, qf[1][0], z1, 0, 0, 0);
      z1 = __builtin_amdgcn_mfma_f32_16x16x32_bf16(kf1, qf[1][1], z1, 0, 0, 0);
      s[0][ct] = z0;
      s[1][ct] = z1;
    }
#pragma unroll
    for (int tt = 0; tt < 2; tt++)
#pragma unroll
      for (int ct = 0; ct < 4; ct++)
#pragma unroll
        for (int r = 0; r < 4; r++) s[tt][ct][r] = exp2f(s[tt][ct][r]);
    // In-register P -> A-frag redistribution (T12-style, zero LDS).
#pragma unroll
    for (int tt = 0; tt < 2; tt++) {
      // wA[ct] = bf16 pair (kv quad*4+0, +1); wB[ct] = (+2, +3); q-col = c.
      int wA[4], wB[4];
#pragma unroll
      for (int ct = 0; ct < 4; ct++) {
        wA[ct] = (int)pkbf_trunc(s[tt][ct][0], s[tt][ct][1]);
        wB[ct] = (int)pkbf_trunc(s[tt][ct][2], s[tt][ct][3]);
      }
      // frag0 (kv 0..31 from ct0,ct1): words j0..j3 at quad q = kv q*8+2j.
      pl32swap(wA[0], wA[1]); pl16swap(wA[0], wA[1]);  // wA0=j0, wA1=j2
      pl32swap(wB[0], wB[1]); pl16swap(wB[0], wB[1]);  // wB0=j1, wB1=j3
      int4v f0 = {wA[0], wB[0], wA[1], wB[1]};
      // frag1 (kv 32..63 from ct2,ct3)
      pl32swap(wA[2], wA[3]); pl16swap(wA[2], wA[3]);
      pl32swap(wB[2], wB[3]); pl16swap(wB[2], wB[3]);
      int4v f1 = {wA[2], wB[2], wA[3], wB[3]};
      short8 pf0 = *(short8*)&f0;
      short8 pf1 = *(short8*)&f1;
#pragma unroll
      for (int ct = 0; ct < 4; ct++) {
        acc[tt][ct] = __builtin_amdgcn_mfma_f32_16x16x32_bf16(pf0, vf[ct][0], acc[tt][ct], 0, 0, 0);
        acc[tt][ct] = __builtin_amdgcn_mfma_f32_16x16x32_bf16(pf1, vf[ct][1], acc[tt][ct], 0, 0, 0);
      }
      acc[tt][4] = __builtin_amdgcn_mfma_f32_16x16x32_bf16(pf0, onesf, acc[tt][4], 0, 0, 0);
      acc[tt][4] = __builtin_amdgcn_mfma_f32_16x16x32_bf16(pf1, onesf, acc[tt][4], 0, 0, 0);
    }
  }
  int n = nh >> 2, h = nh & 3;
#pragma unroll
  for (int tt = 0; tt < 2; tt++) {
    float linv[4] = {1.f, 1.f, 1.f, 1.f};
    if (split == 1) {
#pragma unroll
      for (int r = 0; r < 4; r++)
        linv[r] = 1.0f / __shfl(acc[tt][4][r], lane & 48);
    }
    asm volatile("" ::: "memory");
#pragma unroll
    for (int t = 0; t < 4; t++) {
      int us_[4];
#pragma unroll
      for (int r = 0; r < 4; r++) us_[r] = f2bf_bits(acc[tt][t][r] * linv[r]);
      int xv0 = dppx1i(us_[0]);
      int xv1 = dppx1i(us_[1]);
      int xv2 = dppx1i(us_[2]);
      int xv3 = dppx1i(us_[3]);
      if (ev) {
        *(int*)(pl + (quad * 4 + 0) * 66 + t * 16 + c) = (xv0 << 16) | us_[0];
        *(int*)(pl + (quad * 4 + 1) * 66 + t * 16 + c) = (xv1 << 16) | us_[1];
      } else {
        *(int*)(pl + (quad * 4 + 2) * 66 + t * 16 + (c - 1)) = (us_[2] << 16) | xv2;
        *(int*)(pl + (quad * 4 + 3) * 66 + t * 16 + (c - 1)) = (us_[3] << 16) | xv3;
      }
    }
    asm volatile("" ::: "memory");
    int row = lane >> 2, seg = lane & 3;
    short8 o0 = *(const short8*)(pl + row * 66 + seg * 16);
    short8 o1 = *(const short8*)(pl + row * 66 + seg * 16 + 8);
    short* dst = (short*)po + (size_t)half * 6553600 +
                 ((size_t)n * 1600 + l0 + tt * 16 + row) * 256 + h * 64 + seg * 16;
    *(short8*)(dst) = o0;
    *(short8*)(dst + 8) = o1;
    if (split == 2 && c == 0) {
#pragma unroll
      for (int r = 0; r < 4; r++)
        ls[half * 102400 + nh * 1600 + l0 + tt * 16 + quad * 4 + r] = acc[tt][4][r];
    }
    asm volatile("" ::: "memory");
  }
}

// ---------------------------------------------------------------------------
// K2b: combine split-KV partials (unchanged).
// ---------------------------------------------------------------------------
__global__ void k_comb(const bf16* po_in, const float* __restrict__ ls, bf16* ot) {
  int i = blockIdx.x * 256 + threadIdx.x;
  int ch8 = i & 31;
  int rest = i >> 5;
  int l = rest % 1600;
  int n = rest / 1600;
  int nh = n * 4 + (ch8 >> 3);
  float inv = 1.0f / (ls[nh * 1600 + l] + ls[102400 + nh * 1600 + l]);
  const short* a = (const short*)po_in + (size_t)rest * 256 + ch8 * 8;
  short8 av = *(const short8*)a;
  short8 bv = *(const short8*)(a + 6553600);
  unsigned short o8[8];
#pragma unroll
  for (int j = 0; j < 8; j++) {
    float fa = __uint_as_float(((unsigned)(unsigned short)av[j]) << 16);
    float fb = __uint_as_float(((unsigned)(unsigned short)bv[j]) << 16);
    o8[j] = f2bf_bits((fa + fb) * inv);
  }
  *(short8*)((short*)ot + (size_t)rest * 256 + ch8 * 8) = *(short8*)o8;
}

// ---------------------------------------------------------------------------
// K3: fused (1,9)conv+BN1+res+relu  ->  1x1conv+BN2+res+relu -> d_out.
// Round-15 fusion: the y^T tile built in LDS (formerly for the yt store) IS
// the ff GEMM's A-operand, and outv regs ARE ff's residual -> append 8 MFMAs
// + BN2 epilogue, delete k_ff and all y/yt global traffic.
// grid (50,16), block 128 (2 waves). No __syncthreads.
// ---------------------------------------------------------------------------
__global__ void k_conv9(const bf16* __restrict__ ot, const bf16* __restrict__ Wt,
                        const float* __restrict__ bo, const float* __restrict__ g1,
                        const float* __restrict__ be1, const float* __restrict__ mu1,
                        const float* __restrict__ va1, const float* __restrict__ x,
                        const bf16* __restrict__ WfT, const float* __restrict__ bff,
                        const float* __restrict__ g2, const float* __restrict__ be2,
                        const float* __restrict__ mu2, const float* __restrict__ va2,
                        float* __restrict__ out) {
  __shared__ short tl[2][16 * 66];
  int wv = threadIdx.x >> 6;
  int lane = threadIdx.x & 63;
  int quad = lane >> 4, c = lane & 15;
  int n = blockIdx.y;
  int l0 = blockIdx.x * 32 + wv * 16;
  int la = l0 + c;
  int va = la % 25;
  const short* obase = (const short*)ot + (size_t)n * 409600;
  const short* wbase = (const short*)Wt;
  f32x4 acc[4] = {};
  for (int r = 0; r < 9; r++) {
    int sh = r - 4;
    bool valid = (unsigned)(va + sh) < 25u;
    int lp = la + sh;
    lp = max(0, min(1599, lp));
    const short* arow = obase + (size_t)lp * 256 + quad * 8;
    const short* wrow = wbase + (size_t)r * 8 * 4 * 64 * 8 + lane * 8;
    short8 z8 = {0, 0, 0, 0, 0, 0, 0, 0};
#pragma unroll 4
    for (int kc = 0; kc < 8; kc++) {
      short8 af = *(const short8*)(arow + kc * 32);
      af = valid ? af : z8;
      const short* wk = wrow + kc * 4 * 64 * 8;
      short8 b0 = *(const short8*)(wk);
      short8 b1 = *(const short8*)(wk + 512);
      short8 b2 = *(const short8*)(wk + 1024);
      short8 b3 = *(const short8*)(wk + 1536);
      acc[0] = __builtin_amdgcn_mfma_f32_16x16x32_bf16(af, b0, acc[0], 0, 0, 0);
      acc[1] = __builtin_amdgcn_mfma_f32_16x16x32_bf16(af, b1, acc[1], 0, 0, 0);
      acc[2] = __builtin_amdgcn_mfma_f32_16x16x32_bf16(af, b2, acc[2], 0, 0, 0);
      acc[3] = __builtin_amdgcn_mfma_f32_16x16x32_bf16(af, b3, acc[3], 0, 0, 0);
    }
  }
  // --- epilogue 1: BN1 + bias + residual x + relu -> outv (regs only) ---
  short* tlw = &tl[wv][0];
  float outv[4][4];
#pragma unroll
  for (int cot = 0; cot < 4; cot++) {
    int co = cot * 16 + c;
    float inv = g1[co] * rsqrtf(va1[co] + 1e-5f);
    float add = be1[co] - mu1[co] * inv + bo[co] * inv;
    f32x4 xr = *(const f32x4*)(x + (size_t)(n * 64 + co) * 1600 + l0 + quad * 4);
#pragma unroll
    for (int rr = 0; rr < 4; rr++)
      outv[cot][rr] = fmaxf(acc[cot][rr] * inv + add + xr[rr], 0.f);
  }
  // --- y^T tile via wave-private LDS [16 l][66 ci] (DPP pairing) ---
  asm volatile("" ::: "memory");
  bool ev = (c & 1) == 0;
#pragma unroll
  for (int cot = 0; cot < 4; cot++) {
    int us_[4];
#pragma unroll
    for (int rr = 0; rr < 4; rr++) us_[rr] = f2bf_bits(outv[cot][rr]);
    int xv0 = dppx1i(us_[0]);
    int xv1 = dppx1i(us_[1]);
    int xv2 = dppx1i(us_[2]);
    int xv3 = dppx1i(us_[3]);
    if (ev) {
      *(int*)(tlw + (quad * 4 + 0) * 66 + cot * 16 + c) = (xv0 << 16) | us_[0];
      *(int*)(tlw + (quad * 4 + 1) * 66 + cot * 16 + c) = (xv1 << 16) | us_[1];
    } else {
      *(int*)(tlw + (quad * 4 + 2) * 66 + cot * 16 + (c - 1)) = (us_[2] << 16) | xv2;
      *(int*)(tlw + (quad * 4 + 3) * 66 + cot * 16 + (c - 1)) = (us_[3] << 16) | xv3;
    }
  }
  asm volatile("" ::: "memory");
  // --- fused ff: A-frags straight from tl (A[m=l][k=ci]) ---
  short8 afY0 = *(const short8*)(tlw + c * 66 + quad * 8);
  short8 afY1 = *(const short8*)(tlw + c * 66 + 32 + quad * 8);
  const short* wfb = (const short*)WfT + lane * 8;
  f32x4 acc2[4] = {};
#pragma unroll
  for (int kc = 0; kc < 2; kc++) {
    short8 afk = kc ? afY1 : afY0;
    const short* wk = wfb + kc * 2048;
    short8 b0 = *(const short8*)(wk);
    short8 b1 = *(const short8*)(wk + 512);
    short8 b2 = *(const short8*)(wk + 1024);
    short8 b3 = *(const short8*)(wk + 1536);
    acc2[0] = __builtin_amdgcn_mfma_f32_16x16x32_bf16(afk, b0, acc2[0], 0, 0, 0);
    acc2[1] = __builtin_amdgcn_mfma_f32_16x16x32_bf16(afk, b1, acc2[1], 0, 0, 0);
    acc2[2] = __builtin_amdgcn_mfma_f32_16x16x32_bf16(afk, b2, acc2[2], 0, 0, 0);
    acc2[3] = __builtin_amdgcn_mfma_f32_16x16x32_bf16(afk, b3, acc2[3], 0, 0, 0);
  }
  // --- epilogue 2: BN2 + bias + residual y(=outv) + relu -> d_out fp32 ---
#pragma unroll
  for (int cot = 0; cot < 4; cot++) {
    int co = cot * 16 + c;
    float inv = g2[co] * rsqrtf(va2[co] + 1e-5f);
    float add = be2[co] - mu2[co] * inv + bff[co] * inv;
    f32x4 ov;
#pragma unroll
    for (int rr = 0; rr < 4; rr++)
      ov[rr] = fmaxf(acc2[cot][rr] * inv + add + outv[cot][rr], 0.f);
    *(f32x4*)(out + (size_t)(n * 64 + co) * 1600 + l0 + quad * 4) = ov;
  }
}

extern "C" void kernel_launch(void* const* d_in, const int* in_sizes, int n_in,
                              void* d_out, int out_size, void* d_ws, size_t ws_size,
                              hipStream_t stream) {
  const float* x   = (const float*)d_in[0];
  const float* Wq  = (const float*)d_in[1];
  const float* bq  = (const float*)d_in[2];
  const float* Wo  = (const float*)d_in[3];
  const float* bo  = (const float*)d_in[4];
  const float* g1  = (const float*)d_in[5];
  const float* be1 = (const float*)d_in[6];
  const float* mu1 = (const float*)d_in[7];
  const float* va1 = (const float*)d_in[8];
  const float* Wf  = (const float*)d_in[9];
  const float* bff = (const float*)d_in[10];
  const float* g2  = (const float*)d_in[11];
  const float* be2 = (const float*)d_in[12];
  const float* mu2 = (const float*)d_in[13];
  const float* va2 = (const float*)d_in[14];

  const size_t QKV = (size_t)64 * 1600 * 64;  // 6,553,600 bf16 elems
  // split-2: q,k,vt + po[2] (5*QKV) + weights; ls = 2*102400 f32. ~66.7 MB.
  size_t elems2 = 5 * QKV + 147456 + 4096 + 49152;
  size_t need2 = elems2 * 2 + 2 * 102400 * 4 + 256;
  int split = (ws_size >= need2) ? 2 : 1;

  bf16* qw  = (bf16*)d_ws;
  bf16* kw  = qw + QKV;
  bf16* vtw = kw + QKV;
  bf16* pow_ = vtw + QKV;                      // po half0 == ot for conv9
  bf16* Wt  = pow_ + (size_t)split * QKV;
  bf16* WfT = Wt + 147456;
  bf16* WqT = WfT + 4096;
  float* ls = (float*)(WqT + 49152);           // only touched when split==2

  k_prep<<<576, 256, 0, stream>>>(Wo, Wf, Wq, Wt, WfT, WqT);
  k_qkv<<<1600, 64, 0, stream>>>(x, WqT, bq, qw, kw, vtw);
  k_attn<<<split * 1600, 128, 0, stream>>>(qw, kw, vtw, pow_, ls, split);
  if (split == 2) k_comb<<<3200, 256, 0, stream>>>(pow_, ls, pow_);
  dim3 gc(50, 16);
  k_conv9<<<gc, 128, 0, stream>>>(pow_, Wt, bo, g1, be1, mu1, va1, x,
                                  WfT, bff, g2, be2, mu2, va2, (float*)d_out);
}

// Round 3
// 320.226 us; speedup vs baseline: 1.0052x; 1.0052x over previous
//
#include <hip/hip_runtime.h>
#include <hip/hip_bf16.h>

// Problem constants (fixed by setup_inputs)
#define NB 16     // batch
#define CC 64     // channels
#define TT 64
#define VV 25
#define LL 1600   // T*V
#define HH 4
#define DD 64
#define NH 64     // N*H

// Dtype contract (rounds 0-3): d_in fp32, d_out fp32, tolerance bf16-grade.
// Round-13 lesson: mfma_16x16x16 costs the same cycles as 16x16x32 -> use
// largest-K shapes only. Round-14 lesson: block supply != concurrency.
// Round-16: swapped QK^T + permlane P-redistribution killed the P-LDS
// round-trip (conflicts 4.3M -> 0.5M) but dropping K prefetch made the loop
// latency-bound (120->200us). Round-17: kfb double-buffer + rotation in a
// DYNAMIC loop read conditionally-uninitialized regs (undef) -> inf outputs.
// Round-18 (this round): single kfa buffer; preload kt0; QK^T consumes kfa
// then prefetch OVERWRITES kfa with branchless wraparound index (all loads
// unconditional + in-bounds, zero undef). Prefetch sits between QK^T and
// exp -> consumed next iteration (~250cy cover). No in-loop clobbers.

typedef __hip_bfloat16 bf16;
typedef __attribute__((ext_vector_type(8))) short short8;
typedef __attribute__((ext_vector_type(4))) float f32x4;
typedef __attribute__((ext_vector_type(4))) int int4v;
typedef __attribute__((ext_vector_type(4))) unsigned short us4;

__device__ __forceinline__ float b2f(bf16 v) { return __bfloat162float(v); }
__device__ __forceinline__ unsigned short f2bf_bits(float f) {
  bf16 h = __float2bfloat16(f);
  return *(unsigned short*)&h;
}
// pack two f32 -> bf16x2 by truncation: one v_perm_b32 (validated round 14)
__device__ __forceinline__ unsigned pkbf_trunc(float lo, float hi) {
  return __builtin_amdgcn_perm(__float_as_uint(hi), __float_as_uint(lo), 0x07060302u);
}
// xor-1 lane exchange via DPP quad_perm [1,0,3,2] (0xB1): VALU, not LDS.
__device__ __forceinline__ float dppx1(float x) {
  return __int_as_float(
      __builtin_amdgcn_mov_dpp(__float_as_int(x), 0xB1, 0xF, 0xF, true));
}
__device__ __forceinline__ int dppx1i(int x) {
  return __builtin_amdgcn_mov_dpp(x, 0xB1, 0xF, 0xF, true);
}
// gfx950 dual-register lane swaps (CDNA4): both operands read+written.
// v_permlane32_swap: dst lanes 32-63 <-> src lanes 0-31.
// v_permlane16_swap: dst rows 1,3 (lanes 16-31,48-63) <-> src rows 0,2.
__device__ __forceinline__ void pl32swap(int &a, int &b) {
  asm("v_permlane32_swap_b32 %0, %1" : "+v"(a), "+v"(b));
}
__device__ __forceinline__ void pl16swap(int &a, int &b) {
  asm("v_permlane16_swap_b32 %0, %1" : "+v"(a), "+v"(b));
}

// ---------------------------------------------------------------------------
// K0: weight prep (unchanged).
// ---------------------------------------------------------------------------
__global__ void k_prep(const float* __restrict__ Wo, const float* __restrict__ Wf,
                       const float* __restrict__ Wq,
                       bf16* __restrict__ Wt, bf16* __restrict__ WfT,
                       bf16* __restrict__ WqT) {
  int i = blockIdx.x * 256 + threadIdx.x;
  if (i < 147456) {
    int j = i & 7, lane = (i >> 3) & 63, cot = (i >> 9) & 3;
    int kc = (i >> 11) & 7, r = i >> 14;
    int co = cot * 16 + (lane & 15);
    int ci = kc * 32 + (lane >> 4) * 8 + j;
    Wt[i] = __float2bfloat16(Wo[(co * 256 + ci) * 9 + r]);
  }
  if (i < 4096) {
    int j = i & 7, lane = (i >> 3) & 63, cot = (i >> 9) & 3, kc = (i >> 11) & 1;
    int co = cot * 16 + (lane & 15);
    int ci = kc * 32 + (lane >> 4) * 8 + j;
    WfT[i] = __float2bfloat16(Wf[co * 64 + ci]);
  }
  if (i < 49152) {
    int jj = i & 7, lane = (i >> 3) & 63, g = i >> 9;  // g 0..95
    int nt = g % 48, half = g / 48;
    int ch = half * 32 + (lane >> 4) * 8 + jj;
    int j = nt * 16 + (lane & 15);
    WqT[i] = __float2bfloat16(Wq[ch * 768 + j]);
  }
}

// ---------------------------------------------------------------------------
// K1: qkv projection as MFMA GEMM, round-15: flat 12-group loop with B-frag
// PREFETCH across the transpose clobbers (round-9 trick: clobbers pin the
// issue point early; waits land at next group's MFMAs). Groups 0-3 = q,
// 4-7 = k (tile-transpose epilogue), 8-11 = v (direct stores).
// grid 1600, block 64.
// ---------------------------------------------------------------------------
__global__ __launch_bounds__(64)
void k_qkv(const float* __restrict__ x, const bf16* __restrict__ WqT,
           const float* __restrict__ bq,
           bf16* __restrict__ q, bf16* __restrict__ k, bf16* __restrict__ vt) {
  __shared__ short xa[16 * 72];  // A-tile [16 l][64 c] (+pad)
  __shared__ short tr[16 * 66];  // transpose buffer for q/k epilogue
  int lane = threadIdx.x;
  int quad = lane >> 4, c = lane & 15;
  int n = blockIdx.x / 100;
  int l0 = (blockIdx.x % 100) * 16;
  bool ev = (c & 1) == 0;

  {
    int l = c;
    const float* xb = x + (size_t)n * 102400 + (size_t)(quad * 16) * 1600 + l0 + l;
    unsigned short vb[16];
#pragma unroll
    for (int i = 0; i < 16; i++) vb[i] = f2bf_bits(xb[(size_t)i * 1600]);
    unsigned wrds[8];
#pragma unroll
    for (int i = 0; i < 8; i++)
      wrds[i] = ((unsigned)vb[2 * i + 1] << 16) | vb[2 * i];
    *(short8*)(xa + l * 72 + quad * 16) = *(short8*)&wrds[0];
    *(short8*)(xa + l * 72 + quad * 16 + 8) = *(short8*)&wrds[4];
  }
  asm volatile("" ::: "memory");
  short8 af0 = *(const short8*)(xa + c * 72 + quad * 8);
  short8 af1 = *(const short8*)(xa + c * 72 + 32 + quad * 8);

  const short* wq0 = (const short*)WqT;
  const float QSCALE = 0.125f * 1.44269504f;

  short8 bc[8], bn[8];
#pragma unroll
  for (int t = 0; t < 4; t++) {
    bc[2 * t]     = *(const short8*)(wq0 + ((size_t)t * 64 + lane) * 8);
    bc[2 * t + 1] = *(const short8*)(wq0 + ((size_t)(48 + t) * 64 + lane) * 8);
  }

#pragma unroll
  for (int g = 0; g < 12; g++) {
    int s = g >> 2, h = g & 3;
    // --- 4 output tiles of this group (uses prefetched bc) ---
    f32x4 z[4];
#pragma unroll
    for (int t = 0; t < 4; t++) {
      int nt = g * 4 + t;
      float bv = bq[nt * 16 + c];
      f32x4 zz = {bv, bv, bv, bv};
      zz = __builtin_amdgcn_mfma_f32_16x16x32_bf16(af0, bc[2 * t], zz, 0, 0, 0);
      zz = __builtin_amdgcn_mfma_f32_16x16x32_bf16(af1, bc[2 * t + 1], zz, 0, 0, 0);
      z[t] = zz;
    }
    // --- prefetch group g+1 B-frags BEFORE the clobber section ---
    if (g < 11) {
#pragma unroll
      for (int t = 0; t < 4; t++) {
        int nt = (g + 1) * 4 + t;
        bn[2 * t]     = *(const short8*)(wq0 + ((size_t)nt * 64 + lane) * 8);
        bn[2 * t + 1] = *(const short8*)(wq0 + ((size_t)(48 + nt) * 64 + lane) * 8);
      }
    }
    if (s < 2) {
      // q/k: tile-transpose via tr, coalesced 16B row stores
      asm volatile("" ::: "memory");
#pragma unroll
      for (int t = 0; t < 4; t++) {
        if (s == 0) {
#pragma unroll
          for (int r = 0; r < 4; r++) z[t][r] *= QSCALE;
        }
        int us_[4];
#pragma unroll
        for (int r = 0; r < 4; r++) us_[r] = f2bf_bits(z[t][r]);
        int xv0 = dppx1i(us_[0]);
        int xv1 = dppx1i(us_[1]);
        int xv2 = dppx1i(us_[2]);
        int xv3 = dppx1i(us_[3]);
        if (ev) {
          *(int*)(tr + (quad * 4 + 0) * 66 + t * 16 + c) = (xv0 << 16) | us_[0];
          *(int*)(tr + (quad * 4 + 1) * 66 + t * 16 + c) = (xv1 << 16) | us_[1];
        } else {
          *(int*)(tr + (quad * 4 + 2) * 66 + t * 16 + (c - 1)) = (us_[2] << 16) | xv2;
          *(int*)(tr + (quad * 4 + 3) * 66 + t * 16 + (c - 1)) = (us_[3] << 16) | xv3;
        }
      }
      asm volatile("" ::: "memory");
      int row = lane >> 2, seg = lane & 3;
      short8 o0 = *(const short8*)(tr + row * 66 + seg * 16);
      short8 o1 = *(const short8*)(tr + row * 66 + seg * 16 + 8);
      short* dstp = (short*)(s == 0 ? q : k);
      short* dst = dstp + ((size_t)(n * 4 + h) * 1600 + l0 + row) * 64 + seg * 16;
      *(short8*)(dst) = o0;
      *(short8*)(dst + 8) = o1;
      asm volatile("" ::: "memory");  // tr reused next group
    } else {
      // v: direct stores to vt[nh][d][l]
#pragma unroll
      for (int t = 0; t < 4; t++) {
        us4 pk;
#pragma unroll
        for (int r = 0; r < 4; r++) pk[r] = f2bf_bits(z[t][r]);
        *(us4*)((short*)vt + ((size_t)((n * 4 + h) * 64 + t * 16 + c)) * 1600 +
                l0 + quad * 4) = pk;
      }
    }
#pragma unroll
    for (int i = 0; i < 8; i++) bc[i] = bn[i];
  }
}

// ---------------------------------------------------------------------------
// K2: MFMA flash attention, round-18: barrier-free kt loop, single-buffer
// register K prefetch (no undef, no rotation).
//  - kfa preloaded for kt0; each iteration: QK^T consumes kfa, THEN kfa is
//    overwritten with K[ktn] where ktn wraps to kt0 on the last iteration
//    (branchless, always-valid loads). Consumed next iteration.
//  - QK^T computed SWAPPED: s = mfma(K_frag, Q_frag) => D[m=kv][n=q]; PV
//    A-frags assembled in-register via permlane32/16_swap. No P LDS.
//  - LDS only holds the once-per-block O-transpose epilogue tile.
// grid split*1600, block 128.
// ---------------------------------------------------------------------------
__global__ __launch_bounds__(128, 2)
void k_attn(const bf16* __restrict__ q, const bf16* __restrict__ k,
            const bf16* __restrict__ vt, bf16* __restrict__ po,
            float* __restrict__ ls, int split) {
  __shared__ short pl_all[2][16 * 66];  // epilogue transpose only (wave-private)
  int tid = threadIdx.x;
  int wv = tid >> 6, lane = tid & 63;
  int quad = lane >> 4, c = lane & 15;
  int bid = blockIdx.x;
  int xcd = bid & 7;
  int slot = bid >> 3;
  int half, qt, grp;
  if (split == 2) { half = slot & 1; qt = (slot >> 1) % 25; grp = slot / 50; }
  else            { half = 0;        qt = slot % 25;        grp = slot / 25; }
  int nh = grp * 8 + xcd;          // nh%8 == bid%8 -> per-XCD K/V stream
  int kt0 = half ? 13 : 0;
  int kt1 = (split == 2 && half == 0) ? 13 : 25;
  int l0 = qt * 64 + wv * 32;      // wave's rows: tiles at l0, l0+16
  short* pl = pl_all[wv];

  const short* qbase = (const short*)q + ((size_t)nh * 1600 + l0 + c) * 64 + quad * 8;
  short8 qf[2][2];
  qf[0][0] = *(const short8*)(qbase);
  qf[0][1] = *(const short8*)(qbase + 32);
  qf[1][0] = *(const short8*)(qbase + 16 * 64);
  qf[1][1] = *(const short8*)(qbase + 16 * 64 + 32);

  short ob = (c == 0) ? (short)0x3F80 : (short)0;  // bf16 1.0 in col 0
  short8 onesf = {ob, ob, ob, ob, ob, ob, ob, ob};

  f32x4 acc[2][5] = {};  // per tile: 4 d-tiles + l-tile (ones-trick)

  const short* kg = (const short*)k + (size_t)nh * 102400;
  const short* vg = (const short*)vt + (size_t)nh * 102400;
  bool ev = (c & 1) == 0;

  // preload K frags for kt0 (one-time exposed latency)
  short8 kfa[4][2];
  {
    const short* kr = kg + (size_t)kt0 * 4096;
#pragma unroll
    for (int ct = 0; ct < 4; ct++) {
      const short* kp = kr + (size_t)(ct * 16 + c) * 64 + quad * 8;
      kfa[ct][0] = *(const short8*)(kp);
      kfa[ct][1] = *(const short8*)(kp + 32);
    }
  }

  for (int kt = kt0; kt < kt1; kt++) {
    // V fragments (B operand of PV) for CURRENT kt: covered by QK^T+softmax.
    short8 vf[4][2];
#pragma unroll
    for (int ct = 0; ct < 4; ct++) {
      const short* p0 = vg + (size_t)(ct * 16 + c) * 1600 + kt * 64 + quad * 8;
      vf[ct][0] = *(const short8*)(p0);
      vf[ct][1] = *(const short8*)(p0 + 32);
    }
    // QK^T swapped: s[tt][ct] = D[m=kv(ct tile)][n=q(tile tt)], bias -8.
    f32x4 s[2][4];
#pragma unroll
    for (int ct = 0; ct < 4; ct++) {
      f32x4 z0 = {-8.f, -8.f, -8.f, -8.f}, z1 = {-8.f, -8.f, -8.f, -8.f};
      z0 = __builtin_amdgcn_mfma_f32_16x16x32_bf16(kfa[ct][0], qf[0][0], z0, 0, 0, 0);
      z0 = __builtin_amdgcn_mfma_f32_16x16x32_bf16(kfa[ct][1], qf[0][1], z0, 0, 0, 0);
      z1 = __builtin_amdgcn_mfma_f32_16x16x32_bf16(kfa[ct][0], qf[1][0], z1, 0, 0, 0);
      z1 = __builtin_amdgcn_mfma_f32_16x16x32_bf16(kfa[ct][1], qf[1][1], z1, 0, 0, 0);
      s[0][ct] = z0;
      s[1][ct] = z1;
    }
    // Prefetch K frags for NEXT iteration into kfa (branchless wraparound:
    // last iteration harmlessly reloads kt0 -> all loads valid, zero undef).
    {
      int ktn = (kt + 1 < kt1) ? (kt + 1) : kt0;
      const short* krn = kg + (size_t)ktn * 4096;
#pragma unroll
      for (int ct = 0; ct < 4; ct++) {
        const short* kp = krn + (size_t)(ct * 16 + c) * 64 + quad * 8;
        kfa[ct][0] = *(const short8*)(kp);
        kfa[ct][1] = *(const short8*)(kp + 32);
      }
    }
#pragma unroll
    for (int tt = 0; tt < 2; tt++)
#pragma unroll
      for (int ct = 0; ct < 4; ct++)
#pragma unroll
        for (int r = 0; r < 4; r++) s[tt][ct][r] = exp2f(s[tt][ct][r]);
    // In-register P -> A-frag redistribution (T12-style, zero LDS).
#pragma unroll
    for (int tt = 0; tt < 2; tt++) {
      // wA[ct] = bf16 pair (kv quad*4+0, +1); wB[ct] = (+2, +3); q-col = c.
      int wA[4], wB[4];
#pragma unroll
      for (int ct = 0; ct < 4; ct++) {
        wA[ct] = (int)pkbf_trunc(s[tt][ct][0], s[tt][ct][1]);
        wB[ct] = (int)pkbf_trunc(s[tt][ct][2], s[tt][ct][3]);
      }
      // frag0 (kv 0..31 from ct0,ct1): words j0..j3 at quad q = kv q*8+2j.
      pl32swap(wA[0], wA[1]); pl16swap(wA[0], wA[1]);  // wA0=j0, wA1=j2
      pl32swap(wB[0], wB[1]); pl16swap(wB[0], wB[1]);  // wB0=j1, wB1=j3
      int4v f0 = {wA[0], wB[0], wA[1], wB[1]};
      // frag1 (kv 32..63 from ct2,ct3)
      pl32swap(wA[2], wA[3]); pl16swap(wA[2], wA[3]);
      pl32swap(wB[2], wB[3]); pl16swap(wB[2], wB[3]);
      int4v f1 = {wA[2], wB[2], wA[3], wB[3]};
      short8 pf0 = *(short8*)&f0;
      short8 pf1 = *(short8*)&f1;
#pragma unroll
      for (int ct = 0; ct < 4; ct++) {
        acc[tt][ct] = __builtin_amdgcn_mfma_f32_16x16x32_bf16(pf0, vf[ct][0], acc[tt][ct], 0, 0, 0);
        acc[tt][ct] = __builtin_amdgcn_mfma_f32_16x16x32_bf16(pf1, vf[ct][1], acc[tt][ct], 0, 0, 0);
      }
      acc[tt][4] = __builtin_amdgcn_mfma_f32_16x16x32_bf16(pf0, onesf, acc[tt][4], 0, 0, 0);
      acc[tt][4] = __builtin_amdgcn_mfma_f32_16x16x32_bf16(pf1, onesf, acc[tt][4], 0, 0, 0);
    }
  }
  int n = nh >> 2, h = nh & 3;
#pragma unroll
  for (int tt = 0; tt < 2; tt++) {
    float linv[4] = {1.f, 1.f, 1.f, 1.f};
    if (split == 1) {
#pragma unroll
      for (int r = 0; r < 4; r++)
        linv[r] = 1.0f / __shfl(acc[tt][4][r], lane & 48);
    }
    asm volatile("" ::: "memory");
#pragma unroll
    for (int t = 0; t < 4; t++) {
      int us_[4];
#pragma unroll
      for (int r = 0; r < 4; r++) us_[r] = f2bf_bits(acc[tt][t][r] * linv[r]);
      int xv0 = dppx1i(us_[0]);
      int xv1 = dppx1i(us_[1]);
      int xv2 = dppx1i(us_[2]);
      int xv3 = dppx1i(us_[3]);
      if (ev) {
        *(int*)(pl + (quad * 4 + 0) * 66 + t * 16 + c) = (xv0 << 16) | us_[0];
        *(int*)(pl + (quad * 4 + 1) * 66 + t * 16 + c) = (xv1 << 16) | us_[1];
      } else {
        *(int*)(pl + (quad * 4 + 2) * 66 + t * 16 + (c - 1)) = (us_[2] << 16) | xv2;
        *(int*)(pl + (quad * 4 + 3) * 66 + t * 16 + (c - 1)) = (us_[3] << 16) | xv3;
      }
    }
    asm volatile("" ::: "memory");
    int row = lane >> 2, seg = lane & 3;
    short8 o0 = *(const short8*)(pl + row * 66 + seg * 16);
    short8 o1 = *(const short8*)(pl + row * 66 + seg * 16 + 8);
    short* dst = (short*)po + (size_t)half * 6553600 +
                 ((size_t)n * 1600 + l0 + tt * 16 + row) * 256 + h * 64 + seg * 16;
    *(short8*)(dst) = o0;
    *(short8*)(dst + 8) = o1;
    if (split == 2 && c == 0) {
#pragma unroll
      for (int r = 0; r < 4; r++)
        ls[half * 102400 + nh * 1600 + l0 + tt * 16 + quad * 4 + r] = acc[tt][4][r];
    }
    asm volatile("" ::: "memory");
  }
}

// ---------------------------------------------------------------------------
// K2b: combine split-KV partials (unchanged).
// ---------------------------------------------------------------------------
__global__ void k_comb(const bf16* po_in, const float* __restrict__ ls, bf16* ot) {
  int i = blockIdx.x * 256 + threadIdx.x;
  int ch8 = i & 31;
  int rest = i >> 5;
  int l = rest % 1600;
  int n = rest / 1600;
  int nh = n * 4 + (ch8 >> 3);
  float inv = 1.0f / (ls[nh * 1600 + l] + ls[102400 + nh * 1600 + l]);
  const short* a = (const short*)po_in + (size_t)rest * 256 + ch8 * 8;
  short8 av = *(const short8*)a;
  short8 bv = *(const short8*)(a + 6553600);
  unsigned short o8[8];
#pragma unroll
  for (int j = 0; j < 8; j++) {
    float fa = __uint_as_float(((unsigned)(unsigned short)av[j]) << 16);
    float fb = __uint_as_float(((unsigned)(unsigned short)bv[j]) << 16);
    o8[j] = f2bf_bits((fa + fb) * inv);
  }
  *(short8*)((short*)ot + (size_t)rest * 256 + ch8 * 8) = *(short8*)o8;
}

// ---------------------------------------------------------------------------
// K3: fused (1,9)conv+BN1+res+relu  ->  1x1conv+BN2+res+relu -> d_out.
// Round-15 fusion: the y^T tile built in LDS (formerly for the yt store) IS
// the ff GEMM's A-operand, and outv regs ARE ff's residual -> append 8 MFMAs
// + BN2 epilogue, delete k_ff and all y/yt global traffic.
// grid (50,16), block 128 (2 waves). No __syncthreads.
// ---------------------------------------------------------------------------
__global__ void k_conv9(const bf16* __restrict__ ot, const bf16* __restrict__ Wt,
                        const float* __restrict__ bo, const float* __restrict__ g1,
                        const float* __restrict__ be1, const float* __restrict__ mu1,
                        const float* __restrict__ va1, const float* __restrict__ x,
                        const bf16* __restrict__ WfT, const float* __restrict__ bff,
                        const float* __restrict__ g2, const float* __restrict__ be2,
                        const float* __restrict__ mu2, const float* __restrict__ va2,
                        float* __restrict__ out) {
  __shared__ short tl[2][16 * 66];
  int wv = threadIdx.x >> 6;
  int lane = threadIdx.x & 63;
  int quad = lane >> 4, c = lane & 15;
  int n = blockIdx.y;
  int l0 = blockIdx.x * 32 + wv * 16;
  int la = l0 + c;
  int va = la % 25;
  const short* obase = (const short*)ot + (size_t)n * 409600;
  const short* wbase = (const short*)Wt;
  f32x4 acc[4] = {};
  for (int r = 0; r < 9; r++) {
    int sh = r - 4;
    bool valid = (unsigned)(va + sh) < 25u;
    int lp = la + sh;
    lp = max(0, min(1599, lp));
    const short* arow = obase + (size_t)lp * 256 + quad * 8;
    const short* wrow = wbase + (size_t)r * 8 * 4 * 64 * 8 + lane * 8;
    short8 z8 = {0, 0, 0, 0, 0, 0, 0, 0};
#pragma unroll 4
    for (int kc = 0; kc < 8; kc++) {
      short8 af = *(const short8*)(arow + kc * 32);
      af = valid ? af : z8;
      const short* wk = wrow + kc * 4 * 64 * 8;
      short8 b0 = *(const short8*)(wk);
      short8 b1 = *(const short8*)(wk + 512);
      short8 b2 = *(const short8*)(wk + 1024);
      short8 b3 = *(const short8*)(wk + 1536);
      acc[0] = __builtin_amdgcn_mfma_f32_16x16x32_bf16(af, b0, acc[0], 0, 0, 0);
      acc[1] = __builtin_amdgcn_mfma_f32_16x16x32_bf16(af, b1, acc[1], 0, 0, 0);
      acc[2] = __builtin_amdgcn_mfma_f32_16x16x32_bf16(af, b2, acc[2], 0, 0, 0);
      acc[3] = __builtin_amdgcn_mfma_f32_16x16x32_bf16(af, b3, acc[3], 0, 0, 0);
    }
  }
  // --- epilogue 1: BN1 + bias + residual x + relu -> outv (regs only) ---
  short* tlw = &tl[wv][0];
  float outv[4][4];
#pragma unroll
  for (int cot = 0; cot < 4; cot++) {
    int co = cot * 16 + c;
    float inv = g1[co] * rsqrtf(va1[co] + 1e-5f);
    float add = be1[co] - mu1[co] * inv + bo[co] * inv;
    f32x4 xr = *(const f32x4*)(x + (size_t)(n * 64 + co) * 1600 + l0 + quad * 4);
#pragma unroll
    for (int rr = 0; rr < 4; rr++)
      outv[cot][rr] = fmaxf(acc[cot][rr] * inv + add + xr[rr], 0.f);
  }
  // --- y^T tile via wave-private LDS [16 l][66 ci] (DPP pairing) ---
  asm volatile("" ::: "memory");
  bool ev = (c & 1) == 0;
#pragma unroll
  for (int cot = 0; cot < 4; cot++) {
    int us_[4];
#pragma unroll
    for (int rr = 0; rr < 4; rr++) us_[rr] = f2bf_bits(outv[cot][rr]);
    int xv0 = dppx1i(us_[0]);
    int xv1 = dppx1i(us_[1]);
    int xv2 = dppx1i(us_[2]);
    int xv3 = dppx1i(us_[3]);
    if (ev) {
      *(int*)(tlw + (quad * 4 + 0) * 66 + cot * 16 + c) = (xv0 << 16) | us_[0];
      *(int*)(tlw + (quad * 4 + 1) * 66 + cot * 16 + c) = (xv1 << 16) | us_[1];
    } else {
      *(int*)(tlw + (quad * 4 + 2) * 66 + cot * 16 + (c - 1)) = (us_[2] << 16) | xv2;
      *(int*)(tlw + (quad * 4 + 3) * 66 + cot * 16 + (c - 1)) = (us_[3] << 16) | xv3;
    }
  }
  asm volatile("" ::: "memory");
  // --- fused ff: A-frags straight from tl (A[m=l][k=ci]) ---
  short8 afY0 = *(const short8*)(tlw + c * 66 + quad * 8);
  short8 afY1 = *(const short8*)(tlw + c * 66 + 32 + quad * 8);
  const short* wfb = (const short*)WfT + lane * 8;
  f32x4 acc2[4] = {};
#pragma unroll
  for (int kc = 0; kc < 2; kc++) {
    short8 afk = kc ? afY1 : afY0;
    const short* wk = wfb + kc * 2048;
    short8 b0 = *(const short8*)(wk);
    short8 b1 = *(const short8*)(wk + 512);
    short8 b2 = *(const short8*)(wk + 1024);
    short8 b3 = *(const short8*)(wk + 1536);
    acc2[0] = __builtin_amdgcn_mfma_f32_16x16x32_bf16(afk, b0, acc2[0], 0, 0, 0);
    acc2[1] = __builtin_amdgcn_mfma_f32_16x16x32_bf16(afk, b1, acc2[1], 0, 0, 0);
    acc2[2] = __builtin_amdgcn_mfma_f32_16x16x32_bf16(afk, b2, acc2[2], 0, 0, 0);
    acc2[3] = __builtin_amdgcn_mfma_f32_16x16x32_bf16(afk, b3, acc2[3], 0, 0, 0);
  }
  // --- epilogue 2: BN2 + bias + residual y(=outv) + relu -> d_out fp32 ---
#pragma unroll
  for (int cot = 0; cot < 4; cot++) {
    int co = cot * 16 + c;
    float inv = g2[co] * rsqrtf(va2[co] + 1e-5f);
    float add = be2[co] - mu2[co] * inv + bff[co] * inv;
    f32x4 ov;
#pragma unroll
    for (int rr = 0; rr < 4; rr++)
      ov[rr] = fmaxf(acc2[cot][rr] * inv + add + outv[cot][rr], 0.f);
    *(f32x4*)(out + (size_t)(n * 64 + co) * 1600 + l0 + quad * 4) = ov;
  }
}

extern "C" void kernel_launch(void* const* d_in, const int* in_sizes, int n_in,
                              void* d_out, int out_size, void* d_ws, size_t ws_size,
                              hipStream_t stream) {
  const float* x   = (const float*)d_in[0];
  const float* Wq  = (const float*)d_in[1];
  const float* bq  = (const float*)d_in[2];
  const float* Wo  = (const float*)d_in[3];
  const float* bo  = (const float*)d_in[4];
  const float* g1  = (const float*)d_in[5];
  const float* be1 = (const float*)d_in[6];
  const float* mu1 = (const float*)d_in[7];
  const float* va1 = (const float*)d_in[8];
  const float* Wf  = (const float*)d_in[9];
  const float* bff = (const float*)d_in[10];
  const float* g2  = (const float*)d_in[11];
  const float* be2 = (const float*)d_in[12];
  const float* mu2 = (const float*)d_in[13];
  const float* va2 = (const float*)d_in[14];

  const size_t QKV = (size_t)64 * 1600 * 64;  // 6,553,600 bf16 elems
  // split-2: q,k,vt + po[2] (5*QKV) + weights; ls = 2*102400 f32. ~66.7 MB.
  size_t elems2 = 5 * QKV + 147456 + 4096 + 49152;
  size_t need2 = elems2 * 2 + 2 * 102400 * 4 + 256;
  int split = (ws_size >= need2) ? 2 : 1;

  bf16* qw  = (bf16*)d_ws;
  bf16* kw  = qw + QKV;
  bf16* vtw = kw + QKV;
  bf16* pow_ = vtw + QKV;                      // po half0 == ot for conv9
  bf16* Wt  = pow_ + (size_t)split * QKV;
  bf16* WfT = Wt + 147456;
  bf16* WqT = WfT + 4096;
  float* ls = (float*)(WqT + 49152);           // only touched when split==2

  k_prep<<<576, 256, 0, stream>>>(Wo, Wf, Wq, Wt, WfT, WqT);
  k_qkv<<<1600, 64, 0, stream>>>(x, WqT, bq, qw, kw, vtw);
  k_attn<<<split * 1600, 128, 0, stream>>>(qw, kw, vtw, pow_, ls, split);
  if (split == 2) k_comb<<<3200, 256, 0, stream>>>(pow_, ls, pow_);
  dim3 gc(50, 16);
  k_conv9<<<gc, 128, 0, stream>>>(pow_, Wt, bo, g1, be1, mu1, va1, x,
                                  WfT, bff, g2, be2, mu2, va2, (float*)d_out);
}

// Round 4
// 319.605 us; speedup vs baseline: 1.0071x; 1.0019x over previous
//
#include <hip/hip_runtime.h>
#include <hip/hip_bf16.h>

// Problem constants (fixed by setup_inputs)
#define NB 16     // batch
#define CC 64     // channels
#define TT 64
#define VV 25
#define LL 1600   // T*V
#define HH 4
#define DD 64
#define NH 64     // N*H

// Dtype contract (rounds 0-3): d_in fp32, d_out fp32, tolerance bf16-grade.
// Round-13 lesson: mfma_16x16x16 costs the same cycles as 16x16x32.
// Round-16: swapped QK^T + permlane P-redistribution killed the P-LDS
// round-trip (conflicts 4.3M -> 0.5M) but the loop went latency-bound.
// Round-17: conditional double-buffer rotation = undef -> inf. Round-18:
// wraparound prefetch WITHOUT a pin -> scheduler sank the loads to the
// bottom of the body (VGPR stayed 72, dur unchanged 198us). Round-19 (this
// round): prefetch + PIN. Two asm memory clobbers per iteration: one after
// the V loads (V issue pinned before QK^T; used after exp+permlane), one
// after the wraparound K prefetch (K issue pinned before exp; used next
// iteration). Expect VGPR ~150-190 as proof the prefetch is live across
// the backedge.

typedef __hip_bfloat16 bf16;
typedef __attribute__((ext_vector_type(8))) short short8;
typedef __attribute__((ext_vector_type(4))) float f32x4;
typedef __attribute__((ext_vector_type(4))) int int4v;
typedef __attribute__((ext_vector_type(4))) unsigned short us4;

__device__ __forceinline__ float b2f(bf16 v) { return __bfloat162float(v); }
__device__ __forceinline__ unsigned short f2bf_bits(float f) {
  bf16 h = __float2bfloat16(f);
  return *(unsigned short*)&h;
}
// pack two f32 -> bf16x2 by truncation: one v_perm_b32 (validated round 14)
__device__ __forceinline__ unsigned pkbf_trunc(float lo, float hi) {
  return __builtin_amdgcn_perm(__float_as_uint(hi), __float_as_uint(lo), 0x07060302u);
}
// xor-1 lane exchange via DPP quad_perm [1,0,3,2] (0xB1): VALU, not LDS.
__device__ __forceinline__ float dppx1(float x) {
  return __int_as_float(
      __builtin_amdgcn_mov_dpp(__float_as_int(x), 0xB1, 0xF, 0xF, true));
}
__device__ __forceinline__ int dppx1i(int x) {
  return __builtin_amdgcn_mov_dpp(x, 0xB1, 0xF, 0xF, true);
}
// gfx950 dual-register lane swaps (CDNA4): both operands read+written.
// v_permlane32_swap: dst lanes 32-63 <-> src lanes 0-31.
// v_permlane16_swap: dst rows 1,3 (lanes 16-31,48-63) <-> src rows 0,2.
__device__ __forceinline__ void pl32swap(int &a, int &b) {
  asm("v_permlane32_swap_b32 %0, %1" : "+v"(a), "+v"(b));
}
__device__ __forceinline__ void pl16swap(int &a, int &b) {
  asm("v_permlane16_swap_b32 %0, %1" : "+v"(a), "+v"(b));
}

// ---------------------------------------------------------------------------
// K0: weight prep (unchanged).
// ---------------------------------------------------------------------------
__global__ void k_prep(const float* __restrict__ Wo, const float* __restrict__ Wf,
                       const float* __restrict__ Wq,
                       bf16* __restrict__ Wt, bf16* __restrict__ WfT,
                       bf16* __restrict__ WqT) {
  int i = blockIdx.x * 256 + threadIdx.x;
  if (i < 147456) {
    int j = i & 7, lane = (i >> 3) & 63, cot = (i >> 9) & 3;
    int kc = (i >> 11) & 7, r = i >> 14;
    int co = cot * 16 + (lane & 15);
    int ci = kc * 32 + (lane >> 4) * 8 + j;
    Wt[i] = __float2bfloat16(Wo[(co * 256 + ci) * 9 + r]);
  }
  if (i < 4096) {
    int j = i & 7, lane = (i >> 3) & 63, cot = (i >> 9) & 3, kc = (i >> 11) & 1;
    int co = cot * 16 + (lane & 15);
    int ci = kc * 32 + (lane >> 4) * 8 + j;
    WfT[i] = __float2bfloat16(Wf[co * 64 + ci]);
  }
  if (i < 49152) {
    int jj = i & 7, lane = (i >> 3) & 63, g = i >> 9;  // g 0..95
    int nt = g % 48, half = g / 48;
    int ch = half * 32 + (lane >> 4) * 8 + jj;
    int j = nt * 16 + (lane & 15);
    WqT[i] = __float2bfloat16(Wq[ch * 768 + j]);
  }
}

// ---------------------------------------------------------------------------
// K1: qkv projection as MFMA GEMM, round-15: flat 12-group loop with B-frag
// PREFETCH across the transpose clobbers (round-9 trick: clobbers pin the
// issue point early; waits land at next group's MFMAs). Groups 0-3 = q,
// 4-7 = k (tile-transpose epilogue), 8-11 = v (direct stores).
// grid 1600, block 64.
// ---------------------------------------------------------------------------
__global__ __launch_bounds__(64)
void k_qkv(const float* __restrict__ x, const bf16* __restrict__ WqT,
           const float* __restrict__ bq,
           bf16* __restrict__ q, bf16* __restrict__ k, bf16* __restrict__ vt) {
  __shared__ short xa[16 * 72];  // A-tile [16 l][64 c] (+pad)
  __shared__ short tr[16 * 66];  // transpose buffer for q/k epilogue
  int lane = threadIdx.x;
  int quad = lane >> 4, c = lane & 15;
  int n = blockIdx.x / 100;
  int l0 = (blockIdx.x % 100) * 16;
  bool ev = (c & 1) == 0;

  {
    int l = c;
    const float* xb = x + (size_t)n * 102400 + (size_t)(quad * 16) * 1600 + l0 + l;
    unsigned short vb[16];
#pragma unroll
    for (int i = 0; i < 16; i++) vb[i] = f2bf_bits(xb[(size_t)i * 1600]);
    unsigned wrds[8];
#pragma unroll
    for (int i = 0; i < 8; i++)
      wrds[i] = ((unsigned)vb[2 * i + 1] << 16) | vb[2 * i];
    *(short8*)(xa + l * 72 + quad * 16) = *(short8*)&wrds[0];
    *(short8*)(xa + l * 72 + quad * 16 + 8) = *(short8*)&wrds[4];
  }
  asm volatile("" ::: "memory");
  short8 af0 = *(const short8*)(xa + c * 72 + quad * 8);
  short8 af1 = *(const short8*)(xa + c * 72 + 32 + quad * 8);

  const short* wq0 = (const short*)WqT;
  const float QSCALE = 0.125f * 1.44269504f;

  short8 bc[8], bn[8];
#pragma unroll
  for (int t = 0; t < 4; t++) {
    bc[2 * t]     = *(const short8*)(wq0 + ((size_t)t * 64 + lane) * 8);
    bc[2 * t + 1] = *(const short8*)(wq0 + ((size_t)(48 + t) * 64 + lane) * 8);
  }

#pragma unroll
  for (int g = 0; g < 12; g++) {
    int s = g >> 2, h = g & 3;
    // --- 4 output tiles of this group (uses prefetched bc) ---
    f32x4 z[4];
#pragma unroll
    for (int t = 0; t < 4; t++) {
      int nt = g * 4 + t;
      float bv = bq[nt * 16 + c];
      f32x4 zz = {bv, bv, bv, bv};
      zz = __builtin_amdgcn_mfma_f32_16x16x32_bf16(af0, bc[2 * t], zz, 0, 0, 0);
      zz = __builtin_amdgcn_mfma_f32_16x16x32_bf16(af1, bc[2 * t + 1], zz, 0, 0, 0);
      z[t] = zz;
    }
    // --- prefetch group g+1 B-frags BEFORE the clobber section ---
    if (g < 11) {
#pragma unroll
      for (int t = 0; t < 4; t++) {
        int nt = (g + 1) * 4 + t;
        bn[2 * t]     = *(const short8*)(wq0 + ((size_t)nt * 64 + lane) * 8);
        bn[2 * t + 1] = *(const short8*)(wq0 + ((size_t)(48 + nt) * 64 + lane) * 8);
      }
    }
    if (s < 2) {
      // q/k: tile-transpose via tr, coalesced 16B row stores
      asm volatile("" ::: "memory");
#pragma unroll
      for (int t = 0; t < 4; t++) {
        if (s == 0) {
#pragma unroll
          for (int r = 0; r < 4; r++) z[t][r] *= QSCALE;
        }
        int us_[4];
#pragma unroll
        for (int r = 0; r < 4; r++) us_[r] = f2bf_bits(z[t][r]);
        int xv0 = dppx1i(us_[0]);
        int xv1 = dppx1i(us_[1]);
        int xv2 = dppx1i(us_[2]);
        int xv3 = dppx1i(us_[3]);
        if (ev) {
          *(int*)(tr + (quad * 4 + 0) * 66 + t * 16 + c) = (xv0 << 16) | us_[0];
          *(int*)(tr + (quad * 4 + 1) * 66 + t * 16 + c) = (xv1 << 16) | us_[1];
        } else {
          *(int*)(tr + (quad * 4 + 2) * 66 + t * 16 + (c - 1)) = (us_[2] << 16) | xv2;
          *(int*)(tr + (quad * 4 + 3) * 66 + t * 16 + (c - 1)) = (us_[3] << 16) | xv3;
        }
      }
      asm volatile("" ::: "memory");
      int row = lane >> 2, seg = lane & 3;
      short8 o0 = *(const short8*)(tr + row * 66 + seg * 16);
      short8 o1 = *(const short8*)(tr + row * 66 + seg * 16 + 8);
      short* dstp = (short*)(s == 0 ? q : k);
      short* dst = dstp + ((size_t)(n * 4 + h) * 1600 + l0 + row) * 64 + seg * 16;
      *(short8*)(dst) = o0;
      *(short8*)(dst + 8) = o1;
      asm volatile("" ::: "memory");  // tr reused next group
    } else {
      // v: direct stores to vt[nh][d][l]
#pragma unroll
      for (int t = 0; t < 4; t++) {
        us4 pk;
#pragma unroll
        for (int r = 0; r < 4; r++) pk[r] = f2bf_bits(z[t][r]);
        *(us4*)((short*)vt + ((size_t)((n * 4 + h) * 64 + t * 16 + c)) * 1600 +
                l0 + quad * 4) = pk;
      }
    }
#pragma unroll
    for (int i = 0; i < 8; i++) bc[i] = bn[i];
  }
}

// ---------------------------------------------------------------------------
// K2: MFMA flash attention, round-19: barrier-free kt loop, single-buffer
// wraparound K prefetch (no undef) + ISSUE-POINT PINS (asm memory clobbers).
//  - V loads at top, pinned before QK^T; used after exp+permlane (~250cy).
//  - K prefetch (wraparound index, always-valid) after QK^T, pinned before
//    exp; used next iteration's QK^T (~full iteration).
//  - QK^T swapped: s = mfma(K,Q) => D[m=kv][n=q]; PV A-frags via
//    permlane32/16_swap in-register. No P LDS, no barriers.
// grid split*1600, block 128.
// ---------------------------------------------------------------------------
__global__ __launch_bounds__(128, 2)
void k_attn(const bf16* __restrict__ q, const bf16* __restrict__ k,
            const bf16* __restrict__ vt, bf16* __restrict__ po,
            float* __restrict__ ls, int split) {
  __shared__ short pl_all[2][16 * 66];  // epilogue transpose only (wave-private)
  int tid = threadIdx.x;
  int wv = tid >> 6, lane = tid & 63;
  int quad = lane >> 4, c = lane & 15;
  int bid = blockIdx.x;
  int xcd = bid & 7;
  int slot = bid >> 3;
  int half, qt, grp;
  if (split == 2) { half = slot & 1; qt = (slot >> 1) % 25; grp = slot / 50; }
  else            { half = 0;        qt = slot % 25;        grp = slot / 25; }
  int nh = grp * 8 + xcd;          // nh%8 == bid%8 -> per-XCD K/V stream
  int kt0 = half ? 13 : 0;
  int kt1 = (split == 2 && half == 0) ? 13 : 25;
  int l0 = qt * 64 + wv * 32;      // wave's rows: tiles at l0, l0+16
  short* pl = pl_all[wv];

  const short* qbase = (const short*)q + ((size_t)nh * 1600 + l0 + c) * 64 + quad * 8;
  short8 qf[2][2];
  qf[0][0] = *(const short8*)(qbase);
  qf[0][1] = *(const short8*)(qbase + 32);
  qf[1][0] = *(const short8*)(qbase + 16 * 64);
  qf[1][1] = *(const short8*)(qbase + 16 * 64 + 32);

  short ob = (c == 0) ? (short)0x3F80 : (short)0;  // bf16 1.0 in col 0
  short8 onesf = {ob, ob, ob, ob, ob, ob, ob, ob};

  f32x4 acc[2][5] = {};  // per tile: 4 d-tiles + l-tile (ones-trick)

  const short* kg = (const short*)k + (size_t)nh * 102400;
  const short* vg = (const short*)vt + (size_t)nh * 102400;
  bool ev = (c & 1) == 0;

  // preload K frags for kt0 (one-time exposed latency)
  short8 kfa[4][2];
  {
    const short* kr = kg + (size_t)kt0 * 4096;
#pragma unroll
    for (int ct = 0; ct < 4; ct++) {
      const short* kp = kr + (size_t)(ct * 16 + c) * 64 + quad * 8;
      kfa[ct][0] = *(const short8*)(kp);
      kfa[ct][1] = *(const short8*)(kp + 32);
    }
  }

  for (int kt = kt0; kt < kt1; kt++) {
    // V fragments (B operand of PV) for CURRENT kt.
    short8 vf[4][2];
#pragma unroll
    for (int ct = 0; ct < 4; ct++) {
      const short* p0 = vg + (size_t)(ct * 16 + c) * 1600 + kt * 64 + quad * 8;
      vf[ct][0] = *(const short8*)(p0);
      vf[ct][1] = *(const short8*)(p0 + 32);
    }
    asm volatile("" ::: "memory");  // PIN: V issued before QK^T
    // QK^T swapped: s[tt][ct] = D[m=kv(ct tile)][n=q(tile tt)], bias -8.
    f32x4 s[2][4];
#pragma unroll
    for (int ct = 0; ct < 4; ct++) {
      f32x4 z0 = {-8.f, -8.f, -8.f, -8.f}, z1 = {-8.f, -8.f, -8.f, -8.f};
      z0 = __builtin_amdgcn_mfma_f32_16x16x32_bf16(kfa[ct][0], qf[0][0], z0, 0, 0, 0);
      z0 = __builtin_amdgcn_mfma_f32_16x16x32_bf16(kfa[ct][1], qf[0][1], z0, 0, 0, 0);
      z1 = __builtin_amdgcn_mfma_f32_16x16x32_bf16(kfa[ct][0], qf[1][0], z1, 0, 0, 0);
      z1 = __builtin_amdgcn_mfma_f32_16x16x32_bf16(kfa[ct][1], qf[1][1], z1, 0, 0, 0);
      s[0][ct] = z0;
      s[1][ct] = z1;
    }
    // Prefetch K frags for NEXT iteration into kfa (branchless wraparound:
    // last iteration harmlessly reloads kt0 -> all loads valid, zero undef).
    {
      int ktn = (kt + 1 < kt1) ? (kt + 1) : kt0;
      const short* krn = kg + (size_t)ktn * 4096;
#pragma unroll
      for (int ct = 0; ct < 4; ct++) {
        const short* kp = krn + (size_t)(ct * 16 + c) * 64 + quad * 8;
        kfa[ct][0] = *(const short8*)(kp);
        kfa[ct][1] = *(const short8*)(kp + 32);
      }
    }
    asm volatile("" ::: "memory");  // PIN: K prefetch issued before exp
#pragma unroll
    for (int tt = 0; tt < 2; tt++)
#pragma unroll
      for (int ct = 0; ct < 4; ct++)
#pragma unroll
        for (int r = 0; r < 4; r++) s[tt][ct][r] = exp2f(s[tt][ct][r]);
    // In-register P -> A-frag redistribution (T12-style, zero LDS).
#pragma unroll
    for (int tt = 0; tt < 2; tt++) {
      // wA[ct] = bf16 pair (kv quad*4+0, +1); wB[ct] = (+2, +3); q-col = c.
      int wA[4], wB[4];
#pragma unroll
      for (int ct = 0; ct < 4; ct++) {
        wA[ct] = (int)pkbf_trunc(s[tt][ct][0], s[tt][ct][1]);
        wB[ct] = (int)pkbf_trunc(s[tt][ct][2], s[tt][ct][3]);
      }
      // frag0 (kv 0..31 from ct0,ct1): words j0..j3 at quad q = kv q*8+2j.
      pl32swap(wA[0], wA[1]); pl16swap(wA[0], wA[1]);  // wA0=j0, wA1=j2
      pl32swap(wB[0], wB[1]); pl16swap(wB[0], wB[1]);  // wB0=j1, wB1=j3
      int4v f0 = {wA[0], wB[0], wA[1], wB[1]};
      // frag1 (kv 32..63 from ct2,ct3)
      pl32swap(wA[2], wA[3]); pl16swap(wA[2], wA[3]);
      pl32swap(wB[2], wB[3]); pl16swap(wB[2], wB[3]);
      int4v f1 = {wA[2], wB[2], wA[3], wB[3]};
      short8 pf0 = *(short8*)&f0;
      short8 pf1 = *(short8*)&f1;
#pragma unroll
      for (int ct = 0; ct < 4; ct++) {
        acc[tt][ct] = __builtin_amdgcn_mfma_f32_16x16x32_bf16(pf0, vf[ct][0], acc[tt][ct], 0, 0, 0);
        acc[tt][ct] = __builtin_amdgcn_mfma_f32_16x16x32_bf16(pf1, vf[ct][1], acc[tt][ct], 0, 0, 0);
      }
      acc[tt][4] = __builtin_amdgcn_mfma_f32_16x16x32_bf16(pf0, onesf, acc[tt][4], 0, 0, 0);
      acc[tt][4] = __builtin_amdgcn_mfma_f32_16x16x32_bf16(pf1, onesf, acc[tt][4], 0, 0, 0);
    }
  }
  int n = nh >> 2, h = nh & 3;
#pragma unroll
  for (int tt = 0; tt < 2; tt++) {
    float linv[4] = {1.f, 1.f, 1.f, 1.f};
    if (split == 1) {
#pragma unroll
      for (int r = 0; r < 4; r++)
        linv[r] = 1.0f / __shfl(acc[tt][4][r], lane & 48);
    }
    asm volatile("" ::: "memory");
#pragma unroll
    for (int t = 0; t < 4; t++) {
      int us_[4];
#pragma unroll
      for (int r = 0; r < 4; r++) us_[r] = f2bf_bits(acc[tt][t][r] * linv[r]);
      int xv0 = dppx1i(us_[0]);
      int xv1 = dppx1i(us_[1]);
      int xv2 = dppx1i(us_[2]);
      int xv3 = dppx1i(us_[3]);
      if (ev) {
        *(int*)(pl + (quad * 4 + 0) * 66 + t * 16 + c) = (xv0 << 16) | us_[0];
        *(int*)(pl + (quad * 4 + 1) * 66 + t * 16 + c) = (xv1 << 16) | us_[1];
      } else {
        *(int*)(pl + (quad * 4 + 2) * 66 + t * 16 + (c - 1)) = (us_[2] << 16) | xv2;
        *(int*)(pl + (quad * 4 + 3) * 66 + t * 16 + (c - 1)) = (us_[3] << 16) | xv3;
      }
    }
    asm volatile("" ::: "memory");
    int row = lane >> 2, seg = lane & 3;
    short8 o0 = *(const short8*)(pl + row * 66 + seg * 16);
    short8 o1 = *(const short8*)(pl + row * 66 + seg * 16 + 8);
    short* dst = (short*)po + (size_t)half * 6553600 +
                 ((size_t)n * 1600 + l0 + tt * 16 + row) * 256 + h * 64 + seg * 16;
    *(short8*)(dst) = o0;
    *(short8*)(dst + 8) = o1;
    if (split == 2 && c == 0) {
#pragma unroll
      for (int r = 0; r < 4; r++)
        ls[half * 102400 + nh * 1600 + l0 + tt * 16 + quad * 4 + r] = acc[tt][4][r];
    }
    asm volatile("" ::: "memory");
  }
}

// ---------------------------------------------------------------------------
// K2b: combine split-KV partials (unchanged).
// ---------------------------------------------------------------------------
__global__ void k_comb(const bf16* po_in, const float* __restrict__ ls, bf16* ot) {
  int i = blockIdx.x * 256 + threadIdx.x;
  int ch8 = i & 31;
  int rest = i >> 5;
  int l = rest % 1600;
  int n = rest / 1600;
  int nh = n * 4 + (ch8 >> 3);
  float inv = 1.0f / (ls[nh * 1600 + l] + ls[102400 + nh * 1600 + l]);
  const short* a = (const short*)po_in + (size_t)rest * 256 + ch8 * 8;
  short8 av = *(const short8*)a;
  short8 bv = *(const short8*)(a + 6553600);
  unsigned short o8[8];
#pragma unroll
  for (int j = 0; j < 8; j++) {
    float fa = __uint_as_float(((unsigned)(unsigned short)av[j]) << 16);
    float fb = __uint_as_float(((unsigned)(unsigned short)bv[j]) << 16);
    o8[j] = f2bf_bits((fa + fb) * inv);
  }
  *(short8*)((short*)ot + (size_t)rest * 256 + ch8 * 8) = *(short8*)o8;
}

// ---------------------------------------------------------------------------
// K3: fused (1,9)conv+BN1+res+relu  ->  1x1conv+BN2+res+relu -> d_out.
// Round-15 fusion: the y^T tile built in LDS (formerly for the yt store) IS
// the ff GEMM's A-operand, and outv regs ARE ff's residual -> append 8 MFMAs
// + BN2 epilogue, delete k_ff and all y/yt global traffic.
// grid (50,16), block 128 (2 waves). No __syncthreads.
// ---------------------------------------------------------------------------
__global__ void k_conv9(const bf16* __restrict__ ot, const bf16* __restrict__ Wt,
                        const float* __restrict__ bo, const float* __restrict__ g1,
                        const float* __restrict__ be1, const float* __restrict__ mu1,
                        const float* __restrict__ va1, const float* __restrict__ x,
                        const bf16* __restrict__ WfT, const float* __restrict__ bff,
                        const float* __restrict__ g2, const float* __restrict__ be2,
                        const float* __restrict__ mu2, const float* __restrict__ va2,
                        float* __restrict__ out) {
  __shared__ short tl[2][16 * 66];
  int wv = threadIdx.x >> 6;
  int lane = threadIdx.x & 63;
  int quad = lane >> 4, c = lane & 15;
  int n = blockIdx.y;
  int l0 = blockIdx.x * 32 + wv * 16;
  int la = l0 + c;
  int va = la % 25;
  const short* obase = (const short*)ot + (size_t)n * 409600;
  const short* wbase = (const short*)Wt;
  f32x4 acc[4] = {};
  for (int r = 0; r < 9; r++) {
    int sh = r - 4;
    bool valid = (unsigned)(va + sh) < 25u;
    int lp = la + sh;
    lp = max(0, min(1599, lp));
    const short* arow = obase + (size_t)lp * 256 + quad * 8;
    const short* wrow = wbase + (size_t)r * 8 * 4 * 64 * 8 + lane * 8;
    short8 z8 = {0, 0, 0, 0, 0, 0, 0, 0};
#pragma unroll 4
    for (int kc = 0; kc < 8; kc++) {
      short8 af = *(const short8*)(arow + kc * 32);
      af = valid ? af : z8;
      const short* wk = wrow + kc * 4 * 64 * 8;
      short8 b0 = *(const short8*)(wk);
      short8 b1 = *(const short8*)(wk + 512);
      short8 b2 = *(const short8*)(wk + 1024);
      short8 b3 = *(const short8*)(wk + 1536);
      acc[0] = __builtin_amdgcn_mfma_f32_16x16x32_bf16(af, b0, acc[0], 0, 0, 0);
      acc[1] = __builtin_amdgcn_mfma_f32_16x16x32_bf16(af, b1, acc[1], 0, 0, 0);
      acc[2] = __builtin_amdgcn_mfma_f32_16x16x32_bf16(af, b2, acc[2], 0, 0, 0);
      acc[3] = __builtin_amdgcn_mfma_f32_16x16x32_bf16(af, b3, acc[3], 0, 0, 0);
    }
  }
  // --- epilogue 1: BN1 + bias + residual x + relu -> outv (regs only) ---
  short* tlw = &tl[wv][0];
  float outv[4][4];
#pragma unroll
  for (int cot = 0; cot < 4; cot++) {
    int co = cot * 16 + c;
    float inv = g1[co] * rsqrtf(va1[co] + 1e-5f);
    float add = be1[co] - mu1[co] * inv + bo[co] * inv;
    f32x4 xr = *(const f32x4*)(x + (size_t)(n * 64 + co) * 1600 + l0 + quad * 4);
#pragma unroll
    for (int rr = 0; rr < 4; rr++)
      outv[cot][rr] = fmaxf(acc[cot][rr] * inv + add + xr[rr], 0.f);
  }
  // --- y^T tile via wave-private LDS [16 l][66 ci] (DPP pairing) ---
  asm volatile("" ::: "memory");
  bool ev = (c & 1) == 0;
#pragma unroll
  for (int cot = 0; cot < 4; cot++) {
    int us_[4];
#pragma unroll
    for (int rr = 0; rr < 4; rr++) us_[rr] = f2bf_bits(outv[cot][rr]);
    int xv0 = dppx1i(us_[0]);
    int xv1 = dppx1i(us_[1]);
    int xv2 = dppx1i(us_[2]);
    int xv3 = dppx1i(us_[3]);
    if (ev) {
      *(int*)(tlw + (quad * 4 + 0) * 66 + cot * 16 + c) = (xv0 << 16) | us_[0];
      *(int*)(tlw + (quad * 4 + 1) * 66 + cot * 16 + c) = (xv1 << 16) | us_[1];
    } else {
      *(int*)(tlw + (quad * 4 + 2) * 66 + cot * 16 + (c - 1)) = (us_[2] << 16) | xv2;
      *(int*)(tlw + (quad * 4 + 3) * 66 + cot * 16 + (c - 1)) = (us_[3] << 16) | xv3;
    }
  }
  asm volatile("" ::: "memory");
  // --- fused ff: A-frags straight from tl (A[m=l][k=ci]) ---
  short8 afY0 = *(const short8*)(tlw + c * 66 + quad * 8);
  short8 afY1 = *(const short8*)(tlw + c * 66 + 32 + quad * 8);
  const short* wfb = (const short*)WfT + lane * 8;
  f32x4 acc2[4] = {};
#pragma unroll
  for (int kc = 0; kc < 2; kc++) {
    short8 afk = kc ? afY1 : afY0;
    const short* wk = wfb + kc * 2048;
    short8 b0 = *(const short8*)(wk);
    short8 b1 = *(const short8*)(wk + 512);
    short8 b2 = *(const short8*)(wk + 1024);
    short8 b3 = *(const short8*)(wk + 1536);
    acc2[0] = __builtin_amdgcn_mfma_f32_16x16x32_bf16(afk, b0, acc2[0], 0, 0, 0);
    acc2[1] = __builtin_amdgcn_mfma_f32_16x16x32_bf16(afk, b1, acc2[1], 0, 0, 0);
    acc2[2] = __builtin_amdgcn_mfma_f32_16x16x32_bf16(afk, b2, acc2[2], 0, 0, 0);
    acc2[3] = __builtin_amdgcn_mfma_f32_16x16x32_bf16(afk, b3, acc2[3], 0, 0, 0);
  }
  // --- epilogue 2: BN2 + bias + residual y(=outv) + relu -> d_out fp32 ---
#pragma unroll
  for (int cot = 0; cot < 4; cot++) {
    int co = cot * 16 + c;
    float inv = g2[co] * rsqrtf(va2[co] + 1e-5f);
    float add = be2[co] - mu2[co] * inv + bff[co] * inv;
    f32x4 ov;
#pragma unroll
    for (int rr = 0; rr < 4; rr++)
      ov[rr] = fmaxf(acc2[cot][rr] * inv + add + outv[cot][rr], 0.f);
    *(f32x4*)(out + (size_t)(n * 64 + co) * 1600 + l0 + quad * 4) = ov;
  }
}

extern "C" void kernel_launch(void* const* d_in, const int* in_sizes, int n_in,
                              void* d_out, int out_size, void* d_ws, size_t ws_size,
                              hipStream_t stream) {
  const float* x   = (const float*)d_in[0];
  const float* Wq  = (const float*)d_in[1];
  const float* bq  = (const float*)d_in[2];
  const float* Wo  = (const float*)d_in[3];
  const float* bo  = (const float*)d_in[4];
  const float* g1  = (const float*)d_in[5];
  const float* be1 = (const float*)d_in[6];
  const float* mu1 = (const float*)d_in[7];
  const float* va1 = (const float*)d_in[8];
  const float* Wf  = (const float*)d_in[9];
  const float* bff = (const float*)d_in[10];
  const float* g2  = (const float*)d_in[11];
  const float* be2 = (const float*)d_in[12];
  const float* mu2 = (const float*)d_in[13];
  const float* va2 = (const float*)d_in[14];

  const size_t QKV = (size_t)64 * 1600 * 64;  // 6,553,600 bf16 elems
  // split-2: q,k,vt + po[2] (5*QKV) + weights; ls = 2*102400 f32. ~66.7 MB.
  size_t elems2 = 5 * QKV + 147456 + 4096 + 49152;
  size_t need2 = elems2 * 2 + 2 * 102400 * 4 + 256;
  int split = (ws_size >= need2) ? 2 : 1;

  bf16* qw  = (bf16*)d_ws;
  bf16* kw  = qw + QKV;
  bf16* vtw = kw + QKV;
  bf16* pow_ = vtw + QKV;                      // po half0 == ot for conv9
  bf16* Wt  = pow_ + (size_t)split * QKV;
  bf16* WfT = Wt + 147456;
  bf16* WqT = WfT + 4096;
  float* ls = (float*)(WqT + 49152);           // only touched when split==2

  k_prep<<<576, 256, 0, stream>>>(Wo, Wf, Wq, Wt, WfT, WqT);
  k_qkv<<<1600, 64, 0, stream>>>(x, WqT, bq, qw, kw, vtw);
  k_attn<<<split * 1600, 128, 0, stream>>>(qw, kw, vtw, pow_, ls, split);
  if (split == 2) k_comb<<<3200, 256, 0, stream>>>(pow_, ls, pow_);
  dim3 gc(50, 16);
  k_conv9<<<gc, 128, 0, stream>>>(pow_, Wt, bo, g1, be1, mu1, va1, x,
                                  WfT, bff, g2, be2, mu2, va2, (float*)d_out);
}

// Round 5
// 250.368 us; speedup vs baseline: 1.2856x; 1.2765x over previous
//
#include <hip/hip_runtime.h>
#include <hip/hip_bf16.h>

// Problem constants (fixed by setup_inputs)
#define NB 16     // batch
#define CC 64     // channels
#define TT 64
#define VV 25
#define LL 1600   // T*V
#define HH 4
#define DD 64
#define NH 64     // N*H

// Dtype contract (rounds 0-3): d_in fp32, d_out fp32, tolerance bf16-grade.
// Round-16..19 lessons: (a) swapped QK^T + permlane P-redistribution is
// correct and kills the P-LDS conflicts (4.3M -> 0.49M); (b) register-
// resident K prefetch CANNOT be made to stick from HIP source -- the
// allocator trades the in-flight loads away (VGPR stayed 72-80, loop went
// latency-bound at 182-200us vs 120us baseline); (c) the LDS-staged K path
// (kbuf + 2 barriers + sk global->reg->LDS prefetch) is what actually
// delivers overlap: the barrier fence pins the sk loads a full phase before
// their consuming ds_write. Round-20 (this round): MERGE -- round-0 kbuf
// skeleton + permlane P path, P-LDS round-trip and its fences deleted.

typedef __hip_bfloat16 bf16;
typedef __attribute__((ext_vector_type(8))) short short8;
typedef __attribute__((ext_vector_type(4))) float f32x4;
typedef __attribute__((ext_vector_type(4))) int int4v;
typedef __attribute__((ext_vector_type(4))) unsigned short us4;

__device__ __forceinline__ float b2f(bf16 v) { return __bfloat162float(v); }
__device__ __forceinline__ unsigned short f2bf_bits(float f) {
  bf16 h = __float2bfloat16(f);
  return *(unsigned short*)&h;
}
// pack two f32 -> bf16x2 by truncation: one v_perm_b32 (validated round 14)
__device__ __forceinline__ unsigned pkbf_trunc(float lo, float hi) {
  return __builtin_amdgcn_perm(__float_as_uint(hi), __float_as_uint(lo), 0x07060302u);
}
// xor-1 lane exchange via DPP quad_perm [1,0,3,2] (0xB1): VALU, not LDS.
__device__ __forceinline__ float dppx1(float x) {
  return __int_as_float(
      __builtin_amdgcn_mov_dpp(__float_as_int(x), 0xB1, 0xF, 0xF, true));
}
__device__ __forceinline__ int dppx1i(int x) {
  return __builtin_amdgcn_mov_dpp(x, 0xB1, 0xF, 0xF, true);
}
// gfx950 dual-register lane swaps (CDNA4): both operands read+written.
// v_permlane32_swap: dst lanes 32-63 <-> src lanes 0-31.
// v_permlane16_swap: dst rows 1,3 (lanes 16-31,48-63) <-> src rows 0,2.
__device__ __forceinline__ void pl32swap(int &a, int &b) {
  asm("v_permlane32_swap_b32 %0, %1" : "+v"(a), "+v"(b));
}
__device__ __forceinline__ void pl16swap(int &a, int &b) {
  asm("v_permlane16_swap_b32 %0, %1" : "+v"(a), "+v"(b));
}

// ---------------------------------------------------------------------------
// K0: weight prep (unchanged).
// ---------------------------------------------------------------------------
__global__ void k_prep(const float* __restrict__ Wo, const float* __restrict__ Wf,
                       const float* __restrict__ Wq,
                       bf16* __restrict__ Wt, bf16* __restrict__ WfT,
                       bf16* __restrict__ WqT) {
  int i = blockIdx.x * 256 + threadIdx.x;
  if (i < 147456) {
    int j = i & 7, lane = (i >> 3) & 63, cot = (i >> 9) & 3;
    int kc = (i >> 11) & 7, r = i >> 14;
    int co = cot * 16 + (lane & 15);
    int ci = kc * 32 + (lane >> 4) * 8 + j;
    Wt[i] = __float2bfloat16(Wo[(co * 256 + ci) * 9 + r]);
  }
  if (i < 4096) {
    int j = i & 7, lane = (i >> 3) & 63, cot = (i >> 9) & 3, kc = (i >> 11) & 1;
    int co = cot * 16 + (lane & 15);
    int ci = kc * 32 + (lane >> 4) * 8 + j;
    WfT[i] = __float2bfloat16(Wf[co * 64 + ci]);
  }
  if (i < 49152) {
    int jj = i & 7, lane = (i >> 3) & 63, g = i >> 9;  // g 0..95
    int nt = g % 48, half = g / 48;
    int ch = half * 32 + (lane >> 4) * 8 + jj;
    int j = nt * 16 + (lane & 15);
    WqT[i] = __float2bfloat16(Wq[ch * 768 + j]);
  }
}

// ---------------------------------------------------------------------------
// K1: qkv projection as MFMA GEMM, round-15: flat 12-group loop with B-frag
// PREFETCH across the transpose clobbers (round-9 trick: clobbers pin the
// issue point early; waits land at next group's MFMAs). Groups 0-3 = q,
// 4-7 = k (tile-transpose epilogue), 8-11 = v (direct stores).
// grid 1600, block 64.
// ---------------------------------------------------------------------------
__global__ __launch_bounds__(64)
void k_qkv(const float* __restrict__ x, const bf16* __restrict__ WqT,
           const float* __restrict__ bq,
           bf16* __restrict__ q, bf16* __restrict__ k, bf16* __restrict__ vt) {
  __shared__ short xa[16 * 72];  // A-tile [16 l][64 c] (+pad)
  __shared__ short tr[16 * 66];  // transpose buffer for q/k epilogue
  int lane = threadIdx.x;
  int quad = lane >> 4, c = lane & 15;
  int n = blockIdx.x / 100;
  int l0 = (blockIdx.x % 100) * 16;
  bool ev = (c & 1) == 0;

  {
    int l = c;
    const float* xb = x + (size_t)n * 102400 + (size_t)(quad * 16) * 1600 + l0 + l;
    unsigned short vb[16];
#pragma unroll
    for (int i = 0; i < 16; i++) vb[i] = f2bf_bits(xb[(size_t)i * 1600]);
    unsigned wrds[8];
#pragma unroll
    for (int i = 0; i < 8; i++)
      wrds[i] = ((unsigned)vb[2 * i + 1] << 16) | vb[2 * i];
    *(short8*)(xa + l * 72 + quad * 16) = *(short8*)&wrds[0];
    *(short8*)(xa + l * 72 + quad * 16 + 8) = *(short8*)&wrds[4];
  }
  asm volatile("" ::: "memory");
  short8 af0 = *(const short8*)(xa + c * 72 + quad * 8);
  short8 af1 = *(const short8*)(xa + c * 72 + 32 + quad * 8);

  const short* wq0 = (const short*)WqT;
  const float QSCALE = 0.125f * 1.44269504f;

  short8 bc[8], bn[8];
#pragma unroll
  for (int t = 0; t < 4; t++) {
    bc[2 * t]     = *(const short8*)(wq0 + ((size_t)t * 64 + lane) * 8);
    bc[2 * t + 1] = *(const short8*)(wq0 + ((size_t)(48 + t) * 64 + lane) * 8);
  }

#pragma unroll
  for (int g = 0; g < 12; g++) {
    int s = g >> 2, h = g & 3;
    // --- 4 output tiles of this group (uses prefetched bc) ---
    f32x4 z[4];
#pragma unroll
    for (int t = 0; t < 4; t++) {
      int nt = g * 4 + t;
      float bv = bq[nt * 16 + c];
      f32x4 zz = {bv, bv, bv, bv};
      zz = __builtin_amdgcn_mfma_f32_16x16x32_bf16(af0, bc[2 * t], zz, 0, 0, 0);
      zz = __builtin_amdgcn_mfma_f32_16x16x32_bf16(af1, bc[2 * t + 1], zz, 0, 0, 0);
      z[t] = zz;
    }
    // --- prefetch group g+1 B-frags BEFORE the clobber section ---
    if (g < 11) {
#pragma unroll
      for (int t = 0; t < 4; t++) {
        int nt = (g + 1) * 4 + t;
        bn[2 * t]     = *(const short8*)(wq0 + ((size_t)nt * 64 + lane) * 8);
        bn[2 * t + 1] = *(const short8*)(wq0 + ((size_t)(48 + nt) * 64 + lane) * 8);
      }
    }
    if (s < 2) {
      // q/k: tile-transpose via tr, coalesced 16B row stores
      asm volatile("" ::: "memory");
#pragma unroll
      for (int t = 0; t < 4; t++) {
        if (s == 0) {
#pragma unroll
          for (int r = 0; r < 4; r++) z[t][r] *= QSCALE;
        }
        int us_[4];
#pragma unroll
        for (int r = 0; r < 4; r++) us_[r] = f2bf_bits(z[t][r]);
        int xv0 = dppx1i(us_[0]);
        int xv1 = dppx1i(us_[1]);
        int xv2 = dppx1i(us_[2]);
        int xv3 = dppx1i(us_[3]);
        if (ev) {
          *(int*)(tr + (quad * 4 + 0) * 66 + t * 16 + c) = (xv0 << 16) | us_[0];
          *(int*)(tr + (quad * 4 + 1) * 66 + t * 16 + c) = (xv1 << 16) | us_[1];
        } else {
          *(int*)(tr + (quad * 4 + 2) * 66 + t * 16 + (c - 1)) = (us_[2] << 16) | xv2;
          *(int*)(tr + (quad * 4 + 3) * 66 + t * 16 + (c - 1)) = (us_[3] << 16) | xv3;
        }
      }
      asm volatile("" ::: "memory");
      int row = lane >> 2, seg = lane & 3;
      short8 o0 = *(const short8*)(tr + row * 66 + seg * 16);
      short8 o1 = *(const short8*)(tr + row * 66 + seg * 16 + 8);
      short* dstp = (short*)(s == 0 ? q : k);
      short* dst = dstp + ((size_t)(n * 4 + h) * 1600 + l0 + row) * 64 + seg * 16;
      *(short8*)(dst) = o0;
      *(short8*)(dst + 8) = o1;
      asm volatile("" ::: "memory");  // tr reused next group
    } else {
      // v: direct stores to vt[nh][d][l]
#pragma unroll
      for (int t = 0; t < 4; t++) {
        us4 pk;
#pragma unroll
        for (int r = 0; r < 4; r++) pk[r] = f2bf_bits(z[t][r]);
        *(us4*)((short*)vt + ((size_t)((n * 4 + h) * 64 + t * 16 + c)) * 1600 +
                l0 + quad * 4) = pk;
      }
    }
#pragma unroll
    for (int i = 0; i < 8; i++) bc[i] = bn[i];
  }
}

// ---------------------------------------------------------------------------
// K2: MFMA flash attention, round-20: round-0 kbuf skeleton + permlane P.
//  - K tile staged in LDS via 2 barriers/kt; sk global->reg->LDS prefetch
//    one iteration ahead (barrier fence pins the loads -> real overlap).
//  - QK^T SWAPPED: mfma(K_from_lds, Q) => D[m=kv][n=q]; PV A-frags built
//    in-register via pkbf + permlane32/16_swap. NO per-iter P LDS, no
//    fences; pl_all is epilogue-only.
// grid split*1600, block 128.
// ---------------------------------------------------------------------------
__global__ __launch_bounds__(128, 2)
void k_attn(const bf16* __restrict__ q, const bf16* __restrict__ k,
            const bf16* __restrict__ vt, bf16* __restrict__ po,
            float* __restrict__ ls, int split) {
  __shared__ short kbuf[64 * 72];       // K tile, padded rows
  __shared__ short pl_all[2][16 * 66];  // epilogue transpose only
  int tid = threadIdx.x;
  int wv = tid >> 6, lane = tid & 63;
  int quad = lane >> 4, c = lane & 15;
  int bid = blockIdx.x;
  int xcd = bid & 7;
  int slot = bid >> 3;
  int half, qt, grp;
  if (split == 2) { half = slot & 1; qt = (slot >> 1) % 25; grp = slot / 50; }
  else            { half = 0;        qt = slot % 25;        grp = slot / 25; }
  int nh = grp * 8 + xcd;          // nh%8 == bid%8 -> per-XCD K/V stream
  int kt0 = half ? 13 : 0;
  int kt1 = (split == 2 && half == 0) ? 13 : 25;
  int l0 = qt * 64 + wv * 32;      // wave's rows: tiles at l0, l0+16
  short* pl = pl_all[wv];

  const short* qbase = (const short*)q + ((size_t)nh * 1600 + l0 + c) * 64 + quad * 8;
  short8 qf[2][2];
  qf[0][0] = *(const short8*)(qbase);
  qf[0][1] = *(const short8*)(qbase + 32);
  qf[1][0] = *(const short8*)(qbase + 16 * 64);
  qf[1][1] = *(const short8*)(qbase + 16 * 64 + 32);

  short ob = (c == 0) ? (short)0x3F80 : (short)0;  // bf16 1.0 in col 0
  short8 onesf = {ob, ob, ob, ob, ob, ob, ob, ob};

  f32x4 acc[2][5] = {};  // per tile: 4 d-tiles + l-tile (ones-trick)

  const short* kg = (const short*)k + (size_t)nh * 102400;
  const short* vg = (const short*)vt + (size_t)nh * 102400;
  bool ev = (c & 1) == 0;

  // sk prefetch: K tile for kt0 (global -> regs; written to LDS after barrier)
  short8 sk[4];
  {
    const short8* gk = (const short8*)(kg + kt0 * 4096);
#pragma unroll
    for (int i = 0; i < 4; i++) sk[i] = gk[tid + i * 128];
  }

  for (int kt = kt0; kt < kt1; kt++) {
    __syncthreads();
#pragma unroll
    for (int i = 0; i < 4; i++) {
      int ch = tid + i * 128;
      *(short8*)(kbuf + (ch >> 3) * 72 + (ch & 7) * 8) = sk[i];
    }
    __syncthreads();
    // V fragments (B operand of PV) for CURRENT kt.
    short8 vf[4][2];
#pragma unroll
    for (int ct = 0; ct < 4; ct++) {
      const short* p0 = vg + (size_t)(ct * 16 + c) * 1600 + kt * 64 + quad * 8;
      vf[ct][0] = *(const short8*)(p0);
      vf[ct][1] = *(const short8*)(p0 + 32);
    }
    // sk prefetch for NEXT kt (pinned early by next iteration's barrier;
    // conditional is safe: sk unused after the final iteration).
    if (kt + 1 < kt1) {
      const short8* gk = (const short8*)(kg + (kt + 1) * 4096);
#pragma unroll
      for (int i = 0; i < 4; i++) sk[i] = gk[tid + i * 128];
    }
    // QK^T swapped: s[tt][ct] = D[m=kv(ct tile)][n=q(tile tt)], bias -8.
    f32x4 s[2][4];
#pragma unroll
    for (int ct = 0; ct < 4; ct++) {
      short8 kf0 = *(const short8*)(kbuf + (ct * 16 + c) * 72 + quad * 8);
      short8 kf1 = *(const short8*)(kbuf + (ct * 16 + c) * 72 + 32 + quad * 8);
      f32x4 z0 = {-8.f, -8.f, -8.f, -8.f}, z1 = {-8.f, -8.f, -8.f, -8.f};
      z0 = __builtin_amdgcn_mfma_f32_16x16x32_bf16(kf0, qf[0][0], z0, 0, 0, 0);
      z0 = __builtin_amdgcn_mfma_f32_16x16x32_bf16(kf1, qf[0][1], z0, 0, 0, 0);
      z1 = __builtin_amdgcn_mfma_f32_16x16x32_bf16(kf0, qf[1][0], z1, 0, 0, 0);
      z1 = __builtin_amdgcn_mfma_f32_16x16x32_bf16(kf1, qf[1][1], z1, 0, 0, 0);
      s[0][ct] = z0;
      s[1][ct] = z1;
    }
#pragma unroll
    for (int tt = 0; tt < 2; tt++)
#pragma unroll
      for (int ct = 0; ct < 4; ct++)
#pragma unroll
        for (int r = 0; r < 4; r++) s[tt][ct][r] = exp2f(s[tt][ct][r]);
    // In-register P -> A-frag redistribution (T12-style, zero LDS).
#pragma unroll
    for (int tt = 0; tt < 2; tt++) {
      // wA[ct] = bf16 pair (kv quad*4+0, +1); wB[ct] = (+2, +3); q-col = c.
      int wA[4], wB[4];
#pragma unroll
      for (int ct = 0; ct < 4; ct++) {
        wA[ct] = (int)pkbf_trunc(s[tt][ct][0], s[tt][ct][1]);
        wB[ct] = (int)pkbf_trunc(s[tt][ct][2], s[tt][ct][3]);
      }
      // frag0 (kv 0..31 from ct0,ct1): words j0..j3 at quad q = kv q*8+2j.
      pl32swap(wA[0], wA[1]); pl16swap(wA[0], wA[1]);  // wA0=j0, wA1=j2
      pl32swap(wB[0], wB[1]); pl16swap(wB[0], wB[1]);  // wB0=j1, wB1=j3
      int4v f0 = {wA[0], wB[0], wA[1], wB[1]};
      // frag1 (kv 32..63 from ct2,ct3)
      pl32swap(wA[2], wA[3]); pl16swap(wA[2], wA[3]);
      pl32swap(wB[2], wB[3]); pl16swap(wB[2], wB[3]);
      int4v f1 = {wA[2], wB[2], wA[3], wB[3]};
      short8 pf0 = *(short8*)&f0;
      short8 pf1 = *(short8*)&f1;
#pragma unroll
      for (int ct = 0; ct < 4; ct++) {
        acc[tt][ct] = __builtin_amdgcn_mfma_f32_16x16x32_bf16(pf0, vf[ct][0], acc[tt][ct], 0, 0, 0);
        acc[tt][ct] = __builtin_amdgcn_mfma_f32_16x16x32_bf16(pf1, vf[ct][1], acc[tt][ct], 0, 0, 0);
      }
      acc[tt][4] = __builtin_amdgcn_mfma_f32_16x16x32_bf16(pf0, onesf, acc[tt][4], 0, 0, 0);
      acc[tt][4] = __builtin_amdgcn_mfma_f32_16x16x32_bf16(pf1, onesf, acc[tt][4], 0, 0, 0);
    }
  }
  int n = nh >> 2, h = nh & 3;
#pragma unroll
  for (int tt = 0; tt < 2; tt++) {
    float linv[4] = {1.f, 1.f, 1.f, 1.f};
    if (split == 1) {
#pragma unroll
      for (int r = 0; r < 4; r++)
        linv[r] = 1.0f / __shfl(acc[tt][4][r], lane & 48);
    }
    asm volatile("" ::: "memory");
#pragma unroll
    for (int t = 0; t < 4; t++) {
      int us_[4];
#pragma unroll
      for (int r = 0; r < 4; r++) us_[r] = f2bf_bits(acc[tt][t][r] * linv[r]);
      int xv0 = dppx1i(us_[0]);
      int xv1 = dppx1i(us_[1]);
      int xv2 = dppx1i(us_[2]);
      int xv3 = dppx1i(us_[3]);
      if (ev) {
        *(int*)(pl + (quad * 4 + 0) * 66 + t * 16 + c) = (xv0 << 16) | us_[0];
        *(int*)(pl + (quad * 4 + 1) * 66 + t * 16 + c) = (xv1 << 16) | us_[1];
      } else {
        *(int*)(pl + (quad * 4 + 2) * 66 + t * 16 + (c - 1)) = (us_[2] << 16) | xv2;
        *(int*)(pl + (quad * 4 + 3) * 66 + t * 16 + (c - 1)) = (us_[3] << 16) | xv3;
      }
    }
    asm volatile("" ::: "memory");
    int row = lane >> 2, seg = lane & 3;
    short8 o0 = *(const short8*)(pl + row * 66 + seg * 16);
    short8 o1 = *(const short8*)(pl + row * 66 + seg * 16 + 8);
    short* dst = (short*)po + (size_t)half * 6553600 +
                 ((size_t)n * 1600 + l0 + tt * 16 + row) * 256 + h * 64 + seg * 16;
    *(short8*)(dst) = o0;
    *(short8*)(dst + 8) = o1;
    if (split == 2 && c == 0) {
#pragma unroll
      for (int r = 0; r < 4; r++)
        ls[half * 102400 + nh * 1600 + l0 + tt * 16 + quad * 4 + r] = acc[tt][4][r];
    }
    asm volatile("" ::: "memory");
  }
}

// ---------------------------------------------------------------------------
// K2b: combine split-KV partials (unchanged).
// ---------------------------------------------------------------------------
__global__ void k_comb(const bf16* po_in, const float* __restrict__ ls, bf16* ot) {
  int i = blockIdx.x * 256 + threadIdx.x;
  int ch8 = i & 31;
  int rest = i >> 5;
  int l = rest % 1600;
  int n = rest / 1600;
  int nh = n * 4 + (ch8 >> 3);
  float inv = 1.0f / (ls[nh * 1600 + l] + ls[102400 + nh * 1600 + l]);
  const short* a = (const short*)po_in + (size_t)rest * 256 + ch8 * 8;
  short8 av = *(const short8*)a;
  short8 bv = *(const short8*)(a + 6553600);
  unsigned short o8[8];
#pragma unroll
  for (int j = 0; j < 8; j++) {
    float fa = __uint_as_float(((unsigned)(unsigned short)av[j]) << 16);
    float fb = __uint_as_float(((unsigned)(unsigned short)bv[j]) << 16);
    o8[j] = f2bf_bits((fa + fb) * inv);
  }
  *(short8*)((short*)ot + (size_t)rest * 256 + ch8 * 8) = *(short8*)o8;
}

// ---------------------------------------------------------------------------
// K3: fused (1,9)conv+BN1+res+relu  ->  1x1conv+BN2+res+relu -> d_out.
// Round-15 fusion: the y^T tile built in LDS (formerly for the yt store) IS
// the ff GEMM's A-operand, and outv regs ARE ff's residual -> append 8 MFMAs
// + BN2 epilogue, delete k_ff and all y/yt global traffic.
// grid (50,16), block 128 (2 waves). No __syncthreads.
// ---------------------------------------------------------------------------
__global__ void k_conv9(const bf16* __restrict__ ot, const bf16* __restrict__ Wt,
                        const float* __restrict__ bo, const float* __restrict__ g1,
                        const float* __restrict__ be1, const float* __restrict__ mu1,
                        const float* __restrict__ va1, const float* __restrict__ x,
                        const bf16* __restrict__ WfT, const float* __restrict__ bff,
                        const float* __restrict__ g2, const float* __restrict__ be2,
                        const float* __restrict__ mu2, const float* __restrict__ va2,
                        float* __restrict__ out) {
  __shared__ short tl[2][16 * 66];
  int wv = threadIdx.x >> 6;
  int lane = threadIdx.x & 63;
  int quad = lane >> 4, c = lane & 15;
  int n = blockIdx.y;
  int l0 = blockIdx.x * 32 + wv * 16;
  int la = l0 + c;
  int va = la % 25;
  const short* obase = (const short*)ot + (size_t)n * 409600;
  const short* wbase = (const short*)Wt;
  f32x4 acc[4] = {};
  for (int r = 0; r < 9; r++) {
    int sh = r - 4;
    bool valid = (unsigned)(va + sh) < 25u;
    int lp = la + sh;
    lp = max(0, min(1599, lp));
    const short* arow = obase + (size_t)lp * 256 + quad * 8;
    const short* wrow = wbase + (size_t)r * 8 * 4 * 64 * 8 + lane * 8;
    short8 z8 = {0, 0, 0, 0, 0, 0, 0, 0};
#pragma unroll 4
    for (int kc = 0; kc < 8; kc++) {
      short8 af = *(const short8*)(arow + kc * 32);
      af = valid ? af : z8;
      const short* wk = wrow + kc * 4 * 64 * 8;
      short8 b0 = *(const short8*)(wk);
      short8 b1 = *(const short8*)(wk + 512);
      short8 b2 = *(const short8*)(wk + 1024);
      short8 b3 = *(const short8*)(wk + 1536);
      acc[0] = __builtin_amdgcn_mfma_f32_16x16x32_bf16(af, b0, acc[0], 0, 0, 0);
      acc[1] = __builtin_amdgcn_mfma_f32_16x16x32_bf16(af, b1, acc[1], 0, 0, 0);
      acc[2] = __builtin_amdgcn_mfma_f32_16x16x32_bf16(af, b2, acc[2], 0, 0, 0);
      acc[3] = __builtin_amdgcn_mfma_f32_16x16x32_bf16(af, b3, acc[3], 0, 0, 0);
    }
  }
  // --- epilogue 1: BN1 + bias + residual x + relu -> outv (regs only) ---
  short* tlw = &tl[wv][0];
  float outv[4][4];
#pragma unroll
  for (int cot = 0; cot < 4; cot++) {
    int co = cot * 16 + c;
    float inv = g1[co] * rsqrtf(va1[co] + 1e-5f);
    float add = be1[co] - mu1[co] * inv + bo[co] * inv;
    f32x4 xr = *(const f32x4*)(x + (size_t)(n * 64 + co) * 1600 + l0 + quad * 4);
#pragma unroll
    for (int rr = 0; rr < 4; rr++)
      outv[cot][rr] = fmaxf(acc[cot][rr] * inv + add + xr[rr], 0.f);
  }
  // --- y^T tile via wave-private LDS [16 l][66 ci] (DPP pairing) ---
  asm volatile("" ::: "memory");
  bool ev = (c & 1) == 0;
#pragma unroll
  for (int cot = 0; cot < 4; cot++) {
    int us_[4];
#pragma unroll
    for (int rr = 0; rr < 4; rr++) us_[rr] = f2bf_bits(outv[cot][rr]);
    int xv0 = dppx1i(us_[0]);
    int xv1 = dppx1i(us_[1]);
    int xv2 = dppx1i(us_[2]);
    int xv3 = dppx1i(us_[3]);
    if (ev) {
      *(int*)(tlw + (quad * 4 + 0) * 66 + cot * 16 + c) = (xv0 << 16) | us_[0];
      *(int*)(tlw + (quad * 4 + 1) * 66 + cot * 16 + c) = (xv1 << 16) | us_[1];
    } else {
      *(int*)(tlw + (quad * 4 + 2) * 66 + cot * 16 + (c - 1)) = (us_[2] << 16) | xv2;
      *(int*)(tlw + (quad * 4 + 3) * 66 + cot * 16 + (c - 1)) = (us_[3] << 16) | xv3;
    }
  }
  asm volatile("" ::: "memory");
  // --- fused ff: A-frags straight from tl (A[m=l][k=ci]) ---
  short8 afY0 = *(const short8*)(tlw + c * 66 + quad * 8);
  short8 afY1 = *(const short8*)(tlw + c * 66 + 32 + quad * 8);
  const short* wfb = (const short*)WfT + lane * 8;
  f32x4 acc2[4] = {};
#pragma unroll
  for (int kc = 0; kc < 2; kc++) {
    short8 afk = kc ? afY1 : afY0;
    const short* wk = wfb + kc * 2048;
    short8 b0 = *(const short8*)(wk);
    short8 b1 = *(const short8*)(wk + 512);
    short8 b2 = *(const short8*)(wk + 1024);
    short8 b3 = *(const short8*)(wk + 1536);
    acc2[0] = __builtin_amdgcn_mfma_f32_16x16x32_bf16(afk, b0, acc2[0], 0, 0, 0);
    acc2[1] = __builtin_amdgcn_mfma_f32_16x16x32_bf16(afk, b1, acc2[1], 0, 0, 0);
    acc2[2] = __builtin_amdgcn_mfma_f32_16x16x32_bf16(afk, b2, acc2[2], 0, 0, 0);
    acc2[3] = __builtin_amdgcn_mfma_f32_16x16x32_bf16(afk, b3, acc2[3], 0, 0, 0);
  }
  // --- epilogue 2: BN2 + bias + residual y(=outv) + relu -> d_out fp32 ---
#pragma unroll
  for (int cot = 0; cot < 4; cot++) {
    int co = cot * 16 + c;
    float inv = g2[co] * rsqrtf(va2[co] + 1e-5f);
    float add = be2[co] - mu2[co] * inv + bff[co] * inv;
    f32x4 ov;
#pragma unroll
    for (int rr = 0; rr < 4; rr++)
      ov[rr] = fmaxf(acc2[cot][rr] * inv + add + outv[cot][rr], 0.f);
    *(f32x4*)(out + (size_t)(n * 64 + co) * 1600 + l0 + quad * 4) = ov;
  }
}

extern "C" void kernel_launch(void* const* d_in, const int* in_sizes, int n_in,
                              void* d_out, int out_size, void* d_ws, size_t ws_size,
                              hipStream_t stream) {
  const float* x   = (const float*)d_in[0];
  const float* Wq  = (const float*)d_in[1];
  const float* bq  = (const float*)d_in[2];
  const float* Wo  = (const float*)d_in[3];
  const float* bo  = (const float*)d_in[4];
  const float* g1  = (const float*)d_in[5];
  const float* be1 = (const float*)d_in[6];
  const float* mu1 = (const float*)d_in[7];
  const float* va1 = (const float*)d_in[8];
  const float* Wf  = (const float*)d_in[9];
  const float* bff = (const float*)d_in[10];
  const float* g2  = (const float*)d_in[11];
  const float* be2 = (const float*)d_in[12];
  const float* mu2 = (const float*)d_in[13];
  const float* va2 = (const float*)d_in[14];

  const size_t QKV = (size_t)64 * 1600 * 64;  // 6,553,600 bf16 elems
  // split-2: q,k,vt + po[2] (5*QKV) + weights; ls = 2*102400 f32. ~66.7 MB.
  size_t elems2 = 5 * QKV + 147456 + 4096 + 49152;
  size_t need2 = elems2 * 2 + 2 * 102400 * 4 + 256;
  int split = (ws_size >= need2) ? 2 : 1;

  bf16* qw  = (bf16*)d_ws;
  bf16* kw  = qw + QKV;
  bf16* vtw = kw + QKV;
  bf16* pow_ = vtw + QKV;                      // po half0 == ot for conv9
  bf16* Wt  = pow_ + (size_t)split * QKV;
  bf16* WfT = Wt + 147456;
  bf16* WqT = WfT + 4096;
  float* ls = (float*)(WqT + 49152);           // only touched when split==2

  k_prep<<<576, 256, 0, stream>>>(Wo, Wf, Wq, Wt, WfT, WqT);
  k_qkv<<<1600, 64, 0, stream>>>(x, WqT, bq, qw, kw, vtw);
  k_attn<<<split * 1600, 128, 0, stream>>>(qw, kw, vtw, pow_, ls, split);
  if (split == 2) k_comb<<<3200, 256, 0, stream>>>(pow_, ls, pow_);
  dim3 gc(50, 16);
  k_conv9<<<gc, 128, 0, stream>>>(pow_, Wt, bo, g1, be1, mu1, va1, x,
                                  WfT, bff, g2, be2, mu2, va2, (float*)d_out);
}

// Round 6
// 229.000 us; speedup vs baseline: 1.4056x; 1.0933x over previous
//
#include <hip/hip_runtime.h>
#include <hip/hip_bf16.h>

// Problem constants (fixed by setup_inputs)
#define NB 16     // batch
#define CC 64     // channels
#define TT 64
#define VV 25
#define LL 1600   // T*V
#define HH 4
#define DD 64
#define NH 64     // N*H

// Dtype contract: d_in fp32, d_out fp32, tolerance bf16-grade.
// Round-16..19: permlane P-redistribution correct (P-LDS deleted); register
// K prefetch unpinnable from HIP (allocator sinks it). Round-20: kbuf
// skeleton + permlane P = 113us. Round-21 (this round): the V fragment
// loads were 16B/lane at stride 3200B -- 64 cache lines per instruction,
// 512 L2 transactions per wave-iteration, ~43M 16B L2 requests chip-wide
// (~order of the whole kernel runtime). Stage V through LDS like K:
// coalesced 128B-row loads -> sv regs -> vbuf under the same two barriers;
// fragment reads from LDS (conflict-even 72-short row pad).

typedef __hip_bfloat16 bf16;
typedef __attribute__((ext_vector_type(8))) short short8;
typedef __attribute__((ext_vector_type(4))) float f32x4;
typedef __attribute__((ext_vector_type(4))) int int4v;
typedef __attribute__((ext_vector_type(4))) unsigned short us4;

__device__ __forceinline__ float b2f(bf16 v) { return __bfloat162float(v); }
__device__ __forceinline__ unsigned short f2bf_bits(float f) {
  bf16 h = __float2bfloat16(f);
  return *(unsigned short*)&h;
}
// pack two f32 -> bf16x2 by truncation: one v_perm_b32 (validated round 14)
__device__ __forceinline__ unsigned pkbf_trunc(float lo, float hi) {
  return __builtin_amdgcn_perm(__float_as_uint(hi), __float_as_uint(lo), 0x07060302u);
}
// xor-1 lane exchange via DPP quad_perm [1,0,3,2] (0xB1): VALU, not LDS.
__device__ __forceinline__ float dppx1(float x) {
  return __int_as_float(
      __builtin_amdgcn_mov_dpp(__float_as_int(x), 0xB1, 0xF, 0xF, true));
}
__device__ __forceinline__ int dppx1i(int x) {
  return __builtin_amdgcn_mov_dpp(x, 0xB1, 0xF, 0xF, true);
}
// gfx950 dual-register lane swaps (CDNA4): both operands read+written.
__device__ __forceinline__ void pl32swap(int &a, int &b) {
  asm("v_permlane32_swap_b32 %0, %1" : "+v"(a), "+v"(b));
}
__device__ __forceinline__ void pl16swap(int &a, int &b) {
  asm("v_permlane16_swap_b32 %0, %1" : "+v"(a), "+v"(b));
}

// ---------------------------------------------------------------------------
// K0: weight prep (unchanged).
// ---------------------------------------------------------------------------
__global__ void k_prep(const float* __restrict__ Wo, const float* __restrict__ Wf,
                       const float* __restrict__ Wq,
                       bf16* __restrict__ Wt, bf16* __restrict__ WfT,
                       bf16* __restrict__ WqT) {
  int i = blockIdx.x * 256 + threadIdx.x;
  if (i < 147456) {
    int j = i & 7, lane = (i >> 3) & 63, cot = (i >> 9) & 3;
    int kc = (i >> 11) & 7, r = i >> 14;
    int co = cot * 16 + (lane & 15);
    int ci = kc * 32 + (lane >> 4) * 8 + j;
    Wt[i] = __float2bfloat16(Wo[(co * 256 + ci) * 9 + r]);
  }
  if (i < 4096) {
    int j = i & 7, lane = (i >> 3) & 63, cot = (i >> 9) & 3, kc = (i >> 11) & 1;
    int co = cot * 16 + (lane & 15);
    int ci = kc * 32 + (lane >> 4) * 8 + j;
    WfT[i] = __float2bfloat16(Wf[co * 64 + ci]);
  }
  if (i < 49152) {
    int jj = i & 7, lane = (i >> 3) & 63, g = i >> 9;  // g 0..95
    int nt = g % 48, half = g / 48;
    int ch = half * 32 + (lane >> 4) * 8 + jj;
    int j = nt * 16 + (lane & 15);
    WqT[i] = __float2bfloat16(Wq[ch * 768 + j]);
  }
}

// ---------------------------------------------------------------------------
// K1: qkv projection as MFMA GEMM (unchanged, round-15 structure).
// grid 1600, block 64.
// ---------------------------------------------------------------------------
__global__ __launch_bounds__(64)
void k_qkv(const float* __restrict__ x, const bf16* __restrict__ WqT,
           const float* __restrict__ bq,
           bf16* __restrict__ q, bf16* __restrict__ k, bf16* __restrict__ vt) {
  __shared__ short xa[16 * 72];  // A-tile [16 l][64 c] (+pad)
  __shared__ short tr[16 * 66];  // transpose buffer for q/k epilogue
  int lane = threadIdx.x;
  int quad = lane >> 4, c = lane & 15;
  int n = blockIdx.x / 100;
  int l0 = (blockIdx.x % 100) * 16;
  bool ev = (c & 1) == 0;

  {
    int l = c;
    const float* xb = x + (size_t)n * 102400 + (size_t)(quad * 16) * 1600 + l0 + l;
    unsigned short vb[16];
#pragma unroll
    for (int i = 0; i < 16; i++) vb[i] = f2bf_bits(xb[(size_t)i * 1600]);
    unsigned wrds[8];
#pragma unroll
    for (int i = 0; i < 8; i++)
      wrds[i] = ((unsigned)vb[2 * i + 1] << 16) | vb[2 * i];
    *(short8*)(xa + l * 72 + quad * 16) = *(short8*)&wrds[0];
    *(short8*)(xa + l * 72 + quad * 16 + 8) = *(short8*)&wrds[4];
  }
  asm volatile("" ::: "memory");
  short8 af0 = *(const short8*)(xa + c * 72 + quad * 8);
  short8 af1 = *(const short8*)(xa + c * 72 + 32 + quad * 8);

  const short* wq0 = (const short*)WqT;
  const float QSCALE = 0.125f * 1.44269504f;

  short8 bc[8], bn[8];
#pragma unroll
  for (int t = 0; t < 4; t++) {
    bc[2 * t]     = *(const short8*)(wq0 + ((size_t)t * 64 + lane) * 8);
    bc[2 * t + 1] = *(const short8*)(wq0 + ((size_t)(48 + t) * 64 + lane) * 8);
  }

#pragma unroll
  for (int g = 0; g < 12; g++) {
    int s = g >> 2, h = g & 3;
    // --- 4 output tiles of this group (uses prefetched bc) ---
    f32x4 z[4];
#pragma unroll
    for (int t = 0; t < 4; t++) {
      int nt = g * 4 + t;
      float bv = bq[nt * 16 + c];
      f32x4 zz = {bv, bv, bv, bv};
      zz = __builtin_amdgcn_mfma_f32_16x16x32_bf16(af0, bc[2 * t], zz, 0, 0, 0);
      zz = __builtin_amdgcn_mfma_f32_16x16x32_bf16(af1, bc[2 * t + 1], zz, 0, 0, 0);
      z[t] = zz;
    }
    // --- prefetch group g+1 B-frags BEFORE the clobber section ---
    if (g < 11) {
#pragma unroll
      for (int t = 0; t < 4; t++) {
        int nt = (g + 1) * 4 + t;
        bn[2 * t]     = *(const short8*)(wq0 + ((size_t)nt * 64 + lane) * 8);
        bn[2 * t + 1] = *(const short8*)(wq0 + ((size_t)(48 + nt) * 64 + lane) * 8);
      }
    }
    if (s < 2) {
      // q/k: tile-transpose via tr, coalesced 16B row stores
      asm volatile("" ::: "memory");
#pragma unroll
      for (int t = 0; t < 4; t++) {
        if (s == 0) {
#pragma unroll
          for (int r = 0; r < 4; r++) z[t][r] *= QSCALE;
        }
        int us_[4];
#pragma unroll
        for (int r = 0; r < 4; r++) us_[r] = f2bf_bits(z[t][r]);
        int xv0 = dppx1i(us_[0]);
        int xv1 = dppx1i(us_[1]);
        int xv2 = dppx1i(us_[2]);
        int xv3 = dppx1i(us_[3]);
        if (ev) {
          *(int*)(tr + (quad * 4 + 0) * 66 + t * 16 + c) = (xv0 << 16) | us_[0];
          *(int*)(tr + (quad * 4 + 1) * 66 + t * 16 + c) = (xv1 << 16) | us_[1];
        } else {
          *(int*)(tr + (quad * 4 + 2) * 66 + t * 16 + (c - 1)) = (us_[2] << 16) | xv2;
          *(int*)(tr + (quad * 4 + 3) * 66 + t * 16 + (c - 1)) = (us_[3] << 16) | xv3;
        }
      }
      asm volatile("" ::: "memory");
      int row = lane >> 2, seg = lane & 3;
      short8 o0 = *(const short8*)(tr + row * 66 + seg * 16);
      short8 o1 = *(const short8*)(tr + row * 66 + seg * 16 + 8);
      short* dstp = (short*)(s == 0 ? q : k);
      short* dst = dstp + ((size_t)(n * 4 + h) * 1600 + l0 + row) * 64 + seg * 16;
      *(short8*)(dst) = o0;
      *(short8*)(dst + 8) = o1;
      asm volatile("" ::: "memory");  // tr reused next group
    } else {
      // v: direct stores to vt[nh][d][l]
#pragma unroll
      for (int t = 0; t < 4; t++) {
        us4 pk;
#pragma unroll
        for (int r = 0; r < 4; r++) pk[r] = f2bf_bits(z[t][r]);
        *(us4*)((short*)vt + ((size_t)((n * 4 + h) * 64 + t * 16 + c)) * 1600 +
                l0 + quad * 4) = pk;
      }
    }
#pragma unroll
    for (int i = 0; i < 8; i++) bc[i] = bn[i];
  }
}

// ---------------------------------------------------------------------------
// K2: MFMA flash attention, round-21: kbuf skeleton + permlane P + V staged
// through LDS (coalesced).
//  - K and V tiles staged in LDS under the same 2 barriers/kt; sk+sv
//    global->reg prefetch one iteration ahead (barrier fence pins loads).
//  - V global reads are now 128B-contiguous rows of vt[nh][d][l] (64
//    coalesced lines per block-tile) instead of 512 scattered 16B lines
//    per wave-iteration.
//  - QK^T SWAPPED: mfma(K_from_lds, Q); PV A-frags via permlane. No P LDS.
// grid split*1600, block 128.
// ---------------------------------------------------------------------------
__global__ __launch_bounds__(128, 2)
void k_attn(const bf16* __restrict__ q, const bf16* __restrict__ k,
            const bf16* __restrict__ vt, bf16* __restrict__ po,
            float* __restrict__ ls, int split) {
  __shared__ short kbuf[64 * 72];       // K tile [kv][d], padded rows
  __shared__ short vbuf[64 * 72];       // V tile [d][kv], padded rows
  __shared__ short pl_all[2][16 * 66];  // epilogue transpose only
  int tid = threadIdx.x;
  int wv = tid >> 6, lane = tid & 63;
  int quad = lane >> 4, c = lane & 15;
  int bid = blockIdx.x;
  int xcd = bid & 7;
  int slot = bid >> 3;
  int half, qt, grp;
  if (split == 2) { half = slot & 1; qt = (slot >> 1) % 25; grp = slot / 50; }
  else            { half = 0;        qt = slot % 25;        grp = slot / 25; }
  int nh = grp * 8 + xcd;          // nh%8 == bid%8 -> per-XCD K/V stream
  int kt0 = half ? 13 : 0;
  int kt1 = (split == 2 && half == 0) ? 13 : 25;
  int l0 = qt * 64 + wv * 32;      // wave's rows: tiles at l0, l0+16
  short* pl = pl_all[wv];

  const short* qbase = (const short*)q + ((size_t)nh * 1600 + l0 + c) * 64 + quad * 8;
  short8 qf[2][2];
  qf[0][0] = *(const short8*)(qbase);
  qf[0][1] = *(const short8*)(qbase + 32);
  qf[1][0] = *(const short8*)(qbase + 16 * 64);
  qf[1][1] = *(const short8*)(qbase + 16 * 64 + 32);

  short ob = (c == 0) ? (short)0x3F80 : (short)0;  // bf16 1.0 in col 0
  short8 onesf = {ob, ob, ob, ob, ob, ob, ob, ob};

  f32x4 acc[2][5] = {};  // per tile: 4 d-tiles + l-tile (ones-trick)

  const short* kg = (const short*)k + (size_t)nh * 102400;
  const short* vg = (const short*)vt + (size_t)nh * 102400;
  bool ev = (c & 1) == 0;

  // prefetch K and V tiles for kt0 (global -> regs; LDS-written after barrier)
  short8 sk[4], sv[4];
  {
    const short8* gk = (const short8*)(kg + kt0 * 4096);
#pragma unroll
    for (int i = 0; i < 4; i++) sk[i] = gk[tid + i * 128];
    // V tile: row d = ch>>3 (0..63), 16B seg = ch&7; src row stride 1600
#pragma unroll
    for (int i = 0; i < 4; i++) {
      int ch = tid + i * 128;
      sv[i] = *(const short8*)(vg + (size_t)(ch >> 3) * 1600 + kt0 * 64 + (ch & 7) * 8);
    }
  }

  for (int kt = kt0; kt < kt1; kt++) {
    __syncthreads();
#pragma unroll
    for (int i = 0; i < 4; i++) {
      int ch = tid + i * 128;
      *(short8*)(kbuf + (ch >> 3) * 72 + (ch & 7) * 8) = sk[i];
      *(short8*)(vbuf + (ch >> 3) * 72 + (ch & 7) * 8) = sv[i];
    }
    __syncthreads();
    // prefetch K+V for NEXT kt (pinned by next iteration's barrier;
    // conditional is safe: sk/sv unused after the final iteration).
    if (kt + 1 < kt1) {
      const short8* gk = (const short8*)(kg + (kt + 1) * 4096);
#pragma unroll
      for (int i = 0; i < 4; i++) sk[i] = gk[tid + i * 128];
#pragma unroll
      for (int i = 0; i < 4; i++) {
        int ch = tid + i * 128;
        sv[i] = *(const short8*)(vg + (size_t)(ch >> 3) * 1600 + (kt + 1) * 64 + (ch & 7) * 8);
      }
    }
    // QK^T swapped: s[tt][ct] = D[m=kv(ct tile)][n=q(tile tt)], bias -8.
    f32x4 s[2][4];
#pragma unroll
    for (int ct = 0; ct < 4; ct++) {
      short8 kf0 = *(const short8*)(kbuf + (ct * 16 + c) * 72 + quad * 8);
      short8 kf1 = *(const short8*)(kbuf + (ct * 16 + c) * 72 + 32 + quad * 8);
      f32x4 z0 = {-8.f, -8.f, -8.f, -8.f}, z1 = {-8.f, -8.f, -8.f, -8.f};
      z0 = __builtin_amdgcn_mfma_f32_16x16x32_bf16(kf0, qf[0][0], z0, 0, 0, 0);
      z0 = __builtin_amdgcn_mfma_f32_16x16x32_bf16(kf1, qf[0][1], z0, 0, 0, 0);
      z1 = __builtin_amdgcn_mfma_f32_16x16x32_bf16(kf0, qf[1][0], z1, 0, 0, 0);
      z1 = __builtin_amdgcn_mfma_f32_16x16x32_bf16(kf1, qf[1][1], z1, 0, 0, 0);
      s[0][ct] = z0;
      s[1][ct] = z1;
    }
#pragma unroll
    for (int tt = 0; tt < 2; tt++)
#pragma unroll
      for (int ct = 0; ct < 4; ct++)
#pragma unroll
        for (int r = 0; r < 4; r++) s[tt][ct][r] = exp2f(s[tt][ct][r]);
    // V fragments from LDS (conflict-even pattern, same as kf reads).
    short8 vf[4][2];
#pragma unroll
    for (int ct = 0; ct < 4; ct++) {
      vf[ct][0] = *(const short8*)(vbuf + (ct * 16 + c) * 72 + quad * 8);
      vf[ct][1] = *(const short8*)(vbuf + (ct * 16 + c) * 72 + 32 + quad * 8);
    }
    // In-register P -> A-frag redistribution (T12-style, zero LDS).
#pragma unroll
    for (int tt = 0; tt < 2; tt++) {
      int wA[4], wB[4];
#pragma unroll
      for (int ct = 0; ct < 4; ct++) {
        wA[ct] = (int)pkbf_trunc(s[tt][ct][0], s[tt][ct][1]);
        wB[ct] = (int)pkbf_trunc(s[tt][ct][2], s[tt][ct][3]);
      }
      // frag0 (kv 0..31 from ct0,ct1): words j0..j3 at quad q = kv q*8+2j.
      pl32swap(wA[0], wA[1]); pl16swap(wA[0], wA[1]);  // wA0=j0, wA1=j2
      pl32swap(wB[0], wB[1]); pl16swap(wB[0], wB[1]);  // wB0=j1, wB1=j3
      int4v f0 = {wA[0], wB[0], wA[1], wB[1]};
      // frag1 (kv 32..63 from ct2,ct3)
      pl32swap(wA[2], wA[3]); pl16swap(wA[2], wA[3]);
      pl32swap(wB[2], wB[3]); pl16swap(wB[2], wB[3]);
      int4v f1 = {wA[2], wB[2], wA[3], wB[3]};
      short8 pf0 = *(short8*)&f0;
      short8 pf1 = *(short8*)&f1;
#pragma unroll
      for (int ct = 0; ct < 4; ct++) {
        acc[tt][ct] = __builtin_amdgcn_mfma_f32_16x16x32_bf16(pf0, vf[ct][0], acc[tt][ct], 0, 0, 0);
        acc[tt][ct] = __builtin_amdgcn_mfma_f32_16x16x32_bf16(pf1, vf[ct][1], acc[tt][ct], 0, 0, 0);
      }
      acc[tt][4] = __builtin_amdgcn_mfma_f32_16x16x32_bf16(pf0, onesf, acc[tt][4], 0, 0, 0);
      acc[tt][4] = __builtin_amdgcn_mfma_f32_16x16x32_bf16(pf1, onesf, acc[tt][4], 0, 0, 0);
    }
  }
  int n = nh >> 2, h = nh & 3;
#pragma unroll
  for (int tt = 0; tt < 2; tt++) {
    float linv[4] = {1.f, 1.f, 1.f, 1.f};
    if (split == 1) {
#pragma unroll
      for (int r = 0; r < 4; r++)
        linv[r] = 1.0f / __shfl(acc[tt][4][r], lane & 48);
    }
    asm volatile("" ::: "memory");
#pragma unroll
    for (int t = 0; t < 4; t++) {
      int us_[4];
#pragma unroll
      for (int r = 0; r < 4; r++) us_[r] = f2bf_bits(acc[tt][t][r] * linv[r]);
      int xv0 = dppx1i(us_[0]);
      int xv1 = dppx1i(us_[1]);
      int xv2 = dppx1i(us_[2]);
      int xv3 = dppx1i(us_[3]);
      if (ev) {
        *(int*)(pl + (quad * 4 + 0) * 66 + t * 16 + c) = (xv0 << 16) | us_[0];
        *(int*)(pl + (quad * 4 + 1) * 66 + t * 16 + c) = (xv1 << 16) | us_[1];
      } else {
        *(int*)(pl + (quad * 4 + 2) * 66 + t * 16 + (c - 1)) = (us_[2] << 16) | xv2;
        *(int*)(pl + (quad * 4 + 3) * 66 + t * 16 + (c - 1)) = (us_[3] << 16) | xv3;
      }
    }
    asm volatile("" ::: "memory");
    int row = lane >> 2, seg = lane & 3;
    short8 o0 = *(const short8*)(pl + row * 66 + seg * 16);
    short8 o1 = *(const short8*)(pl + row * 66 + seg * 16 + 8);
    short* dst = (short*)po + (size_t)half * 6553600 +
                 ((size_t)n * 1600 + l0 + tt * 16 + row) * 256 + h * 64 + seg * 16;
    *(short8*)(dst) = o0;
    *(short8*)(dst + 8) = o1;
    if (split == 2 && c == 0) {
#pragma unroll
      for (int r = 0; r < 4; r++)
        ls[half * 102400 + nh * 1600 + l0 + tt * 16 + quad * 4 + r] = acc[tt][4][r];
    }
    asm volatile("" ::: "memory");
  }
}

// ---------------------------------------------------------------------------
// K2b: combine split-KV partials (unchanged).
// ---------------------------------------------------------------------------
__global__ void k_comb(const bf16* po_in, const float* __restrict__ ls, bf16* ot) {
  int i = blockIdx.x * 256 + threadIdx.x;
  int ch8 = i & 31;
  int rest = i >> 5;
  int l = rest % 1600;
  int n = rest / 1600;
  int nh = n * 4 + (ch8 >> 3);
  float inv = 1.0f / (ls[nh * 1600 + l] + ls[102400 + nh * 1600 + l]);
  const short* a = (const short*)po_in + (size_t)rest * 256 + ch8 * 8;
  short8 av = *(const short8*)a;
  short8 bv = *(const short8*)(a + 6553600);
  unsigned short o8[8];
#pragma unroll
  for (int j = 0; j < 8; j++) {
    float fa = __uint_as_float(((unsigned)(unsigned short)av[j]) << 16);
    float fb = __uint_as_float(((unsigned)(unsigned short)bv[j]) << 16);
    o8[j] = f2bf_bits((fa + fb) * inv);
  }
  *(short8*)((short*)ot + (size_t)rest * 256 + ch8 * 8) = *(short8*)o8;
}

// ---------------------------------------------------------------------------
// K3: fused (1,9)conv+BN1+res+relu  ->  1x1conv+BN2+res+relu -> d_out.
// (unchanged, round-15 structure) grid (50,16), block 128.
// ---------------------------------------------------------------------------
__global__ void k_conv9(const bf16* __restrict__ ot, const bf16* __restrict__ Wt,
                        const float* __restrict__ bo, const float* __restrict__ g1,
                        const float* __restrict__ be1, const float* __restrict__ mu1,
                        const float* __restrict__ va1, const float* __restrict__ x,
                        const bf16* __restrict__ WfT, const float* __restrict__ bff,
                        const float* __restrict__ g2, const float* __restrict__ be2,
                        const float* __restrict__ mu2, const float* __restrict__ va2,
                        float* __restrict__ out) {
  __shared__ short tl[2][16 * 66];
  int wv = threadIdx.x >> 6;
  int lane = threadIdx.x & 63;
  int quad = lane >> 4, c = lane & 15;
  int n = blockIdx.y;
  int l0 = blockIdx.x * 32 + wv * 16;
  int la = l0 + c;
  int va = la % 25;
  const short* obase = (const short*)ot + (size_t)n * 409600;
  const short* wbase = (const short*)Wt;
  f32x4 acc[4] = {};
  for (int r = 0; r < 9; r++) {
    int sh = r - 4;
    bool valid = (unsigned)(va + sh) < 25u;
    int lp = la + sh;
    lp = max(0, min(1599, lp));
    const short* arow = obase + (size_t)lp * 256 + quad * 8;
    const short* wrow = wbase + (size_t)r * 8 * 4 * 64 * 8 + lane * 8;
    short8 z8 = {0, 0, 0, 0, 0, 0, 0, 0};
#pragma unroll 4
    for (int kc = 0; kc < 8; kc++) {
      short8 af = *(const short8*)(arow + kc * 32);
      af = valid ? af : z8;
      const short* wk = wrow + kc * 4 * 64 * 8;
      short8 b0 = *(const short8*)(wk);
      short8 b1 = *(const short8*)(wk + 512);
      short8 b2 = *(const short8*)(wk + 1024);
      short8 b3 = *(const short8*)(wk + 1536);
      acc[0] = __builtin_amdgcn_mfma_f32_16x16x32_bf16(af, b0, acc[0], 0, 0, 0);
      acc[1] = __builtin_amdgcn_mfma_f32_16x16x32_bf16(af, b1, acc[1], 0, 0, 0);
      acc[2] = __builtin_amdgcn_mfma_f32_16x16x32_bf16(af, b2, acc[2], 0, 0, 0);
      acc[3] = __builtin_amdgcn_mfma_f32_16x16x32_bf16(af, b3, acc[3], 0, 0, 0);
    }
  }
  // --- epilogue 1: BN1 + bias + residual x + relu -> outv (regs only) ---
  short* tlw = &tl[wv][0];
  float outv[4][4];
#pragma unroll
  for (int cot = 0; cot < 4; cot++) {
    int co = cot * 16 + c;
    float inv = g1[co] * rsqrtf(va1[co] + 1e-5f);
    float add = be1[co] - mu1[co] * inv + bo[co] * inv;
    f32x4 xr = *(const f32x4*)(x + (size_t)(n * 64 + co) * 1600 + l0 + quad * 4);
#pragma unroll
    for (int rr = 0; rr < 4; rr++)
      outv[cot][rr] = fmaxf(acc[cot][rr] * inv + add + xr[rr], 0.f);
  }
  // --- y^T tile via wave-private LDS [16 l][66 ci] (DPP pairing) ---
  asm volatile("" ::: "memory");
  bool ev = (c & 1) == 0;
#pragma unroll
  for (int cot = 0; cot < 4; cot++) {
    int us_[4];
#pragma unroll
    for (int rr = 0; rr < 4; rr++) us_[rr] = f2bf_bits(outv[cot][rr]);
    int xv0 = dppx1i(us_[0]);
    int xv1 = dppx1i(us_[1]);
    int xv2 = dppx1i(us_[2]);
    int xv3 = dppx1i(us_[3]);
    if (ev) {
      *(int*)(tlw + (quad * 4 + 0) * 66 + cot * 16 + c) = (xv0 << 16) | us_[0];
      *(int*)(tlw + (quad * 4 + 1) * 66 + cot * 16 + c) = (xv1 << 16) | us_[1];
    } else {
      *(int*)(tlw + (quad * 4 + 2) * 66 + cot * 16 + (c - 1)) = (us_[2] << 16) | xv2;
      *(int*)(tlw + (quad * 4 + 3) * 66 + cot * 16 + (c - 1)) = (us_[3] << 16) | xv3;
    }
  }
  asm volatile("" ::: "memory");
  // --- fused ff: A-frags straight from tl (A[m=l][k=ci]) ---
  short8 afY0 = *(const short8*)(tlw + c * 66 + quad * 8);
  short8 afY1 = *(const short8*)(tlw + c * 66 + 32 + quad * 8);
  const short* wfb = (const short*)WfT + lane * 8;
  f32x4 acc2[4] = {};
#pragma unroll
  for (int kc = 0; kc < 2; kc++) {
    short8 afk = kc ? afY1 : afY0;
    const short* wk = wfb + kc * 2048;
    short8 b0 = *(const short8*)(wk);
    short8 b1 = *(const short8*)(wk + 512);
    short8 b2 = *(const short8*)(wk + 1024);
    short8 b3 = *(const short8*)(wk + 1536);
    acc2[0] = __builtin_amdgcn_mfma_f32_16x16x32_bf16(afk, b0, acc2[0], 0, 0, 0);
    acc2[1] = __builtin_amdgcn_mfma_f32_16x16x32_bf16(afk, b1, acc2[1], 0, 0, 0);
    acc2[2] = __builtin_amdgcn_mfma_f32_16x16x32_bf16(afk, b2, acc2[2], 0, 0, 0);
    acc2[3] = __builtin_amdgcn_mfma_f32_16x16x32_bf16(afk, b3, acc2[3], 0, 0, 0);
  }
  // --- epilogue 2: BN2 + bias + residual y(=outv) + relu -> d_out fp32 ---
#pragma unroll
  for (int cot = 0; cot < 4; cot++) {
    int co = cot * 16 + c;
    float inv = g2[co] * rsqrtf(va2[co] + 1e-5f);
    float add = be2[co] - mu2[co] * inv + bff[co] * inv;
    f32x4 ov;
#pragma unroll
    for (int rr = 0; rr < 4; rr++)
      ov[rr] = fmaxf(acc2[cot][rr] * inv + add + outv[cot][rr], 0.f);
    *(f32x4*)(out + (size_t)(n * 64 + co) * 1600 + l0 + quad * 4) = ov;
  }
}

extern "C" void kernel_launch(void* const* d_in, const int* in_sizes, int n_in,
                              void* d_out, int out_size, void* d_ws, size_t ws_size,
                              hipStream_t stream) {
  const float* x   = (const float*)d_in[0];
  const float* Wq  = (const float*)d_in[1];
  const float* bq  = (const float*)d_in[2];
  const float* Wo  = (const float*)d_in[3];
  const float* bo  = (const float*)d_in[4];
  const float* g1  = (const float*)d_in[5];
  const float* be1 = (const float*)d_in[6];
  const float* mu1 = (const float*)d_in[7];
  const float* va1 = (const float*)d_in[8];
  const float* Wf  = (const float*)d_in[9];
  const float* bff = (const float*)d_in[10];
  const float* g2  = (const float*)d_in[11];
  const float* be2 = (const float*)d_in[12];
  const float* mu2 = (const float*)d_in[13];
  const float* va2 = (const float*)d_in[14];

  const size_t QKV = (size_t)64 * 1600 * 64;  // 6,553,600 bf16 elems
  // split-2: q,k,vt + po[2] (5*QKV) + weights; ls = 2*102400 f32. ~66.7 MB.
  size_t elems2 = 5 * QKV + 147456 + 4096 + 49152;
  size_t need2 = elems2 * 2 + 2 * 102400 * 4 + 256;
  int split = (ws_size >= need2) ? 2 : 1;

  bf16* qw  = (bf16*)d_ws;
  bf16* kw  = qw + QKV;
  bf16* vtw = kw + QKV;
  bf16* pow_ = vtw + QKV;                      // po half0 == ot for conv9
  bf16* Wt  = pow_ + (size_t)split * QKV;
  bf16* WfT = Wt + 147456;
  bf16* WqT = WfT + 4096;
  float* ls = (float*)(WqT + 49152);           // only touched when split==2

  k_prep<<<576, 256, 0, stream>>>(Wo, Wf, Wq, Wt, WfT, WqT);
  k_qkv<<<1600, 64, 0, stream>>>(x, WqT, bq, qw, kw, vtw);
  k_attn<<<split * 1600, 128, 0, stream>>>(qw, kw, vtw, pow_, ls, split);
  if (split == 2) k_comb<<<3200, 256, 0, stream>>>(pow_, ls, pow_);
  dim3 gc(50, 16);
  k_conv9<<<gc, 128, 0, stream>>>(pow_, Wt, bo, g1, be1, mu1, va1, x,
                                  WfT, bff, g2, be2, mu2, va2, (float*)d_out);
}